// Round 8
// baseline (288.134 us; speedup 1.0000x reference)
//
#include <hip/hip_runtime.h>
#include <hip/hip_bf16.h>

#define NN 4096
#define NITER 4
#define NSWEEP 5
#define MCS 68     // mailbox/Wc column stride (floats); [64] holds the column's squared norm

// workspace float layout (double-buffered CG vectors INCLUDING y)
#define OFF_STS  64
#define OFF_QRHO (OFF_STS + NN)
#define OFF_DINV (OFF_QRHO + NN)
#define OFF_Y0   (OFF_DINV + NN)
#define OFF_Y1   (OFF_Y0 + NN)
#define OFF_X0   (OFF_Y1 + NN)
#define OFF_X1   (OFF_X0 + NN)
#define OFF_R0   (OFF_X1 + NN)
#define OFF_R1   (OFF_R0 + NN)
#define OFF_P0   (OFF_R1 + NN)
#define OFF_P1   (OFF_P0 + NN)
// per-block pTy partials, double-buffered by iteration parity
#define OFF_PTY0 (OFF_P1 + NN)
#define OFF_PTY1 (OFF_PTY0 + 1024)
#define DH_OFF_BYTES 196608
#define WS_NEED_BF16 (DH_OFF_BYTES + (size_t)NN * NN * 2)

typedef unsigned int uint;
__device__ inline float lo2f(uint w){ return __uint_as_float(w << 16); }
__device__ inline float hi2f(uint w){ return __uint_as_float(w & 0xffff0000u); }
__device__ inline uint f2b(float f){
    uint u = __float_as_uint(f);
    return (u + 0x7FFFu + ((u >> 16) & 1u)) >> 16;   // RNE
}
// 8-lane sum via DPP only (VALU latency, no DS pipe). Valid when the 8 lanes
// of a group are an aligned 8-lane half-row (group g = lanes 8g..8g+7).
// Levels: xor1 (quad_perm 1,0,3,2), xor2 (quad_perm 2,3,0,1),
// row_half_mirror (= xor7 on quad-uniform values -> completes the 8-lane sum).
__device__ inline float rsum8(float x){
    int a = __builtin_amdgcn_update_dpp(0, __float_as_int(x), 0xB1, 0xF, 0xF, true);
    float s = x + __int_as_float(a);
    int b = __builtin_amdgcn_update_dpp(0, __float_as_int(s), 0x4E, 0xF, 0xF, true);
    s = s + __int_as_float(b);
    int c = __builtin_amdgcn_update_dpp(0, __float_as_int(s), 0x141, 0xF, 0xF, true);  // row_half_mirror
    s = s + __int_as_float(c);
    return s;
}

// ---------------- prep (FALLBACK PATH ONLY): StS + b + approx diag + CG init ----------------
__global__ void k_prep(const float* __restrict__ inp, const float* __restrict__ L,
                       const int*  __restrict__ mask, const float* __restrict__ thP,
                       const float* __restrict__ S,
                       const float* __restrict__ l2p, const float* __restrict__ rhop,
                       float* __restrict__ wf){
    int t = blockIdx.x * 256 + threadIdx.x;   // 4096 threads
    int r = t >> 6, c = t & 63;
    float acc = 0.f, acc2 = 0.f;
    for(int h = 0; h < 64; ++h){
        float sr = S[h*64 + r];
        float sc = S[h*64 + c];
        acc  += sr * sc;
        acc2 += sc * sc;
    }
    wf[OFF_STS + t] = acc;
    float rho = rhop[0], l2 = l2p[0];
    float q = (mask[t] != 0) ? 1.f : 0.f;
    float bi = rho * (L[t] - thP[t]) + q * inp[t];
    float dinv = 1.f / (q + rho + l2 * acc2);   // preconditioner only
    wf[OFF_QRHO + t] = q + rho;
    wf[OFF_DINV + t] = dinv;
    wf[OFF_X0 + t]   = 0.f;
    wf[OFF_R0 + t]   = bi;
    wf[OFF_P0 + t]   = bi * dinv;
}

// ---------------- per-block redundant CG scalar update (no fences needed) ----------------
// pTy of the previous iteration arrives as 1024 per-block partials; its sum is
// folded into the first shuffle-reduction tree (red[0..3]=rz, red[4..7]=pTy).
__device__ inline void cg_prologue(float* __restrict__ wf,
                                   const float* __restrict__ rold, const float* __restrict__ pold,
                                   const float* __restrict__ xold, const float* __restrict__ yold,
                                   float* __restrict__ rnew, float* __restrict__ pnew,
                                   float* __restrict__ xnew,
                                   const float* __restrict__ pty_read,
                                   float* __restrict__ psh,
                                   float* __restrict__ red){
    int tid = threadIdx.x;
    const float* dinv = wf + OFF_DINV;
    float4 r4[4], d4[4];
    float part = 0.f;
    #pragma unroll
    for(int k = 0; k < 4; ++k){
        r4[k] = ((const float4*)rold)[tid + k*256];
        d4[k] = ((const float4*)dinv)[tid + k*256];
        part += r4[k].x*r4[k].x*d4[k].x + r4[k].y*r4[k].y*d4[k].y
              + r4[k].z*r4[k].z*d4[k].z + r4[k].w*r4[k].w*d4[k].w;
    }
    float pp = pty_read[tid] + pty_read[tid+256] + pty_read[tid+512] + pty_read[tid+768];
    for(int m = 32; m >= 1; m >>= 1){
        part += __shfl_xor(part, m, 64);
        pp   += __shfl_xor(pp, m, 64);
    }
    int wave = tid >> 6, lane = tid & 63;
    if(lane == 0){ red[wave] = part; red[4+wave] = pp; }
    __syncthreads();
    float rzold = red[0] + red[1] + red[2] + red[3];
    float ptys  = red[4] + red[5] + red[6] + red[7];
    float alpha = rzold / ptys;
    float4 rn[4], zn[4];
    float part2 = 0.f;
    #pragma unroll
    for(int k = 0; k < 4; ++k){
        float4 y4 = ((const float4*)yold)[tid + k*256];
        rn[k].x = r4[k].x - alpha*y4.x;  rn[k].y = r4[k].y - alpha*y4.y;
        rn[k].z = r4[k].z - alpha*y4.z;  rn[k].w = r4[k].w - alpha*y4.w;
        zn[k].x = rn[k].x*d4[k].x;  zn[k].y = rn[k].y*d4[k].y;
        zn[k].z = rn[k].z*d4[k].z;  zn[k].w = rn[k].w*d4[k].w;
        part2 += rn[k].x*zn[k].x + rn[k].y*zn[k].y + rn[k].z*zn[k].z + rn[k].w*zn[k].w;
    }
    for(int m = 32; m >= 1; m >>= 1) part2 += __shfl_xor(part2, m, 64);
    __syncthreads();                      // all reads of red done
    if(lane == 0) red[wave] = part2;
    __syncthreads();
    float rznew = red[0] + red[1] + red[2] + red[3];
    float beta = rznew / rzold;
    bool b0 = (blockIdx.x == 0);
    #pragma unroll
    for(int k = 0; k < 4; ++k){
        float4 po = ((const float4*)pold)[tid + k*256];
        float4 pn;
        pn.x = zn[k].x + beta*po.x;  pn.y = zn[k].y + beta*po.y;
        pn.z = zn[k].z + beta*po.z;  pn.w = zn[k].w + beta*po.w;
        ((float4*)psh)[tid + k*256] = pn;
        if(b0){
            ((float4*)pnew)[tid + k*256] = pn;
            ((float4*)rnew)[tid + k*256] = rn[k];
            float4 xo = ((const float4*)xold)[tid + k*256];
            float4 xn;
            xn.x = xo.x + alpha*po.x;  xn.y = xo.y + alpha*po.y;
            xn.z = xo.z + alpha*po.z;  xn.w = xo.w + alpha*po.w;
            ((float4*)xnew)[tid + k*256] = xn;
        }
    }
    __syncthreads();
}

// ---------------- merged prep + CG step 0: fp32 D matvec + emit bf16 Dh ----------------
__launch_bounds__(256)
__global__ void k_fc(const float* __restrict__ D, unsigned short* __restrict__ Dh,
                     const float* __restrict__ inp, const float* __restrict__ L,
                     const int*  __restrict__ mask, const float* __restrict__ thP,
                     const float* __restrict__ S,
                     const float* __restrict__ l1p, const float* __restrict__ l2p,
                     const float* __restrict__ rhop,
                     float* __restrict__ wf, float* __restrict__ pty_out){
    __shared__ float psh[NN];
    __shared__ float red[8];
    __shared__ float cparts[256];
    int tid = threadIdx.x;
    int wave = tid >> 6, lane = tid & 63;
    int row = blockIdx.x * 4 + wave;
    int u = row & 63, h = row >> 6;
    float l1 = l1p[0], l2 = l2p[0], rho = rhop[0];

    // S column-norm^2 partials (for dinv): wave w covers hh = 16w..16w+15
    {
        float cp = 0.f;
        for(int hh = wave*16; hh < wave*16 + 16; ++hh){
            float sv = S[hh*64 + lane];
            cp += sv * sv;
        }
        cparts[wave*64 + lane] = cp;
    }
    // StS row u (this wave's row), element 'lane'  (S is 16KB -> L1-hot)
    float stv = 0.f;
    for(int hh = 0; hh < 64; ++hh)
        stv += S[hh*64 + u] * S[hh*64 + lane];
    if(row < 64) wf[OFF_STS + row*64 + lane] = stv;   // canonical StS (blocks 0..15)
    __syncthreads();

    // build p0 into psh (redundant per block); canonical inits from blocks 0..15
    int c = tid & 63;
    float cs4 = cparts[c] + cparts[64+c] + cparts[128+c] + cparts[192+c];
    bool canon = (blockIdx.x < 16);
    for(int k = 0; k < 16; ++k){
        int t = tid + k*256;                    // t&63 == tid&63
        float q = (mask[t] != 0) ? 1.f : 0.f;
        float bi = rho * (L[t] - thP[t]) + q * inp[t];
        float dinv = 1.f / (q + rho + l2 * cs4);
        psh[t] = bi * dinv;
        if(canon && k == (int)blockIdx.x){
            wf[OFF_QRHO + t] = q + rho;
            wf[OFF_DINV + t] = dinv;
            wf[OFF_X0 + t]   = 0.f;
            wf[OFF_R0 + t]   = bi;
            wf[OFF_P0 + t]   = bi * dinv;
        }
    }
    __syncthreads();

    // fp32 matvec + emit bf16 Dh
    const float* Drow = D + (size_t)row * NN;
    unsigned short* Dhrow = Dh + (size_t)row * NN;
    float dacc = 0.f;
    for(int j = 0; j < 16; ++j){
        int c0 = j*256 + lane*4;
        float4 dv = *(const float4*)(Drow + c0);
        float4 pa = *(const float4*)(psh + c0);
        dacc += dv.x*pa.x + dv.y*pa.y + dv.z*pa.z + dv.w*pa.w;
        uint2 o;
        o.x = f2b(dv.x) | (f2b(dv.y) << 16);
        o.y = f2b(dv.z) | (f2b(dv.w) << 16);
        *(uint2*)(Dhrow + c0) = o;
    }
    float sacc = stv * psh[h*64 + lane];
    float val = l1 * dacc + l2 * sacc;
    for(int m = 32; m >= 1; m >>= 1) val += __shfl_xor(val, m, 64);
    if(lane == 0){
        float qr = ((mask[row] != 0) ? 1.f : 0.f) + rho;   // local (canonical QRHO may race in-kernel)
        float yi = val + qr * psh[row];
        (wf + OFF_Y0)[row] = yi;
        red[wave] = yi * psh[row];
    }
    __syncthreads();
    if(tid == 0) pty_out[blockIdx.x] = red[0] + red[1] + red[2] + red[3];
}

// ---------------- CG step j>=1: prologue + y = A p (bf16 D) + pTy partial ----------------
__launch_bounds__(256)
__global__ void k_step_h(const unsigned short* __restrict__ Dh,
                         const float* __restrict__ l1p, const float* __restrict__ l2p,
                         float* __restrict__ wf,
                         const float* __restrict__ rold, const float* __restrict__ pold,
                         const float* __restrict__ xold, const float* __restrict__ yold,
                         float* __restrict__ rnew, float* __restrict__ pnew,
                         float* __restrict__ xnew, float* __restrict__ ynew,
                         const float* __restrict__ pty_read, float* __restrict__ pty_write){
    __shared__ float psh[NN];
    __shared__ float red[8];
    int tid = threadIdx.x;
    cg_prologue(wf, rold, pold, xold, yold, rnew, pnew, xnew, pty_read, psh, red);

    float l1 = l1p[0], l2 = l2p[0];
    int wave = tid >> 6, lane = tid & 63;
    int row = blockIdx.x * 4 + wave;
    int h = row >> 6, u = row & 63;
    const float* qrho = wf + OFF_QRHO;
    const float* StS  = wf + OFF_STS;

    const unsigned short* Drow = Dh + (size_t)row * NN;
    float dacc = 0.f;
    for(int j = 0; j < 8; ++j){
        int c0 = j*512 + lane*8;
        uint4 dv = *(const uint4*)(Drow + c0);
        float4 pa = *(const float4*)(psh + c0);
        float4 pb = *(const float4*)(psh + c0 + 4);
        dacc += lo2f(dv.x)*pa.x + hi2f(dv.x)*pa.y
              + lo2f(dv.y)*pa.z + hi2f(dv.y)*pa.w
              + lo2f(dv.z)*pb.x + hi2f(dv.z)*pb.y
              + lo2f(dv.w)*pb.z + hi2f(dv.w)*pb.w;
    }
    float sacc = StS[u*64 + lane] * psh[h*64 + lane];
    float val = l1 * dacc + l2 * sacc;
    for(int m = 32; m >= 1; m >>= 1) val += __shfl_xor(val, m, 64);
    if(lane == 0){
        float yi = val + qrho[row] * psh[row];
        ynew[row] = yi;
        red[wave] = yi * psh[row];
    }
    __syncthreads();
    if(tid == 0) pty_write[blockIdx.x] = red[0] + red[1] + red[2] + red[3];
}

// ---------------- CG step fp32 fallback (do_pro selects prologue) ----------------
__launch_bounds__(256)
__global__ void k_step_f(const float* __restrict__ D,
                         const float* __restrict__ l1p, const float* __restrict__ l2p,
                         float* __restrict__ wf,
                         const float* __restrict__ rold, const float* __restrict__ pold,
                         const float* __restrict__ xold, const float* __restrict__ yold,
                         float* __restrict__ rnew, float* __restrict__ pnew,
                         float* __restrict__ xnew, float* __restrict__ ynew,
                         const float* __restrict__ pty_read, float* __restrict__ pty_write,
                         int do_pro){
    __shared__ float psh[NN];
    __shared__ float red[8];
    int tid = threadIdx.x;
    if(do_pro){
        cg_prologue(wf, rold, pold, xold, yold, rnew, pnew, xnew, pty_read, psh, red);
    } else {
        for(int k = 0; k < 4; ++k)
            ((float4*)psh)[tid + k*256] = ((const float4*)pold)[tid + k*256];
        __syncthreads();
    }
    float l1 = l1p[0], l2 = l2p[0];
    int wave = tid >> 6, lane = tid & 63;
    int row = blockIdx.x * 4 + wave;
    int h = row >> 6, u = row & 63;
    const float* qrho = wf + OFF_QRHO;
    const float* StS  = wf + OFF_STS;
    const float* Drow = D + (size_t)row * NN;
    float dacc = 0.f;
    for(int j = 0; j < 16; ++j){
        int c0 = j*256 + lane*4;
        float4 dv = *(const float4*)(Drow + c0);
        float4 pa = *(const float4*)(psh + c0);
        dacc += dv.x*pa.x + dv.y*pa.y + dv.z*pa.z + dv.w*pa.w;
    }
    float sacc = StS[u*64 + lane] * psh[h*64 + lane];
    float val = l1 * dacc + l2 * sacc;
    for(int m = 32; m >= 1; m >>= 1) val += __shfl_xor(val, m, 64);
    if(lane == 0){
        float yi = val + qrho[row] * psh[row];
        ynew[row] = yi;
        red[wave] = yi * psh[row];
    }
    __syncthreads();
    if(tid == 0) pty_write[blockIdx.x] = red[0] + red[1] + red[2] + red[3];
}

// ---------------- SVT: register-resident Brent-Luk Jacobi + final CG update fused ----------------
// 256 threads = 32 groups x 8 sublanes; each sublane owns 8 rows (two float4s)
// of the pair's two columns. 4 waves = exactly 1 wave/SIMD: halves the per-SIMD
// VALU issue vs the 512-thr version (the angle/reduction/addr overhead was
// replicated per wave with 2 waves/SIMD competing for the same issue port).
// Group reductions are 3-level rsum8; barrier syncs 4 waves instead of 8.
#define P_MA(par) (POOL + (par)*2176)
#define P_MB(par) (POOL + 4352 + (par)*2176)
#define P_XSH     (POOL + 8704)
#define P_TSH     (POOL)
#define P_WC      (POOL + 4352)
#define DOT4(u,v) ((u).x*(v).x + (u).y*(v).y + (u).z*(v).z + (u).w*(v).w)

__launch_bounds__(256)
__global__ void k_svt(const float* __restrict__ thP, const float* __restrict__ vp,
                      const float* __restrict__ netap,
                      float* __restrict__ wf,
                      const float* __restrict__ rlast, const float* __restrict__ plast,
                      const float* __restrict__ xlast,
                      const float* __restrict__ ptyp,
                      float* __restrict__ out){
    __shared__ float POOL[12800];
    __shared__ float s2[64], coef3[64];
    __shared__ float smax_sh;
    __shared__ float redv[8];
    int tid = threadIdx.x;
    float* Xsh = P_XSH;

    // fused final CG update: alpha_last = rz_last / pTy_last ; X = x + alpha*p + thP
    {
        const float* dinv = wf + OFF_DINV;
        float part = 0.f;
        #pragma unroll
        for(int k = 0; k < 4; ++k){
            float4 r4 = ((const float4*)rlast)[tid + k*256];
            float4 d4 = ((const float4*)dinv)[tid + k*256];
            part += r4.x*r4.x*d4.x + r4.y*r4.y*d4.y + r4.z*r4.z*d4.z + r4.w*r4.w*d4.w;
        }
        float pp = ptyp[tid] + ptyp[tid+256] + ptyp[tid+512] + ptyp[tid+768];
        for(int m = 32; m >= 1; m >>= 1){
            part += __shfl_xor(part, m, 64);
            pp   += __shfl_xor(pp, m, 64);
        }
        int wave = tid >> 6;
        if((tid & 63) == 0){ redv[wave] = part; redv[4+wave] = pp; }
        __syncthreads();
        float rz   = redv[0] + redv[1] + redv[2] + redv[3];
        float ptys = redv[4] + redv[5] + redv[6] + redv[7];
        float a = rz / ptys;
        #pragma unroll
        for(int k = 0; k < 4; ++k){
            float4 x4 = ((const float4*)xlast)[tid + k*256];
            float4 p4 = ((const float4*)plast)[tid + k*256];
            float4 t4 = ((const float4*)thP)[tid + k*256];
            float4 v;
            v.x = x4.x + a*p4.x + t4.x;  v.y = x4.y + a*p4.y + t4.y;
            v.z = x4.z + a*p4.z + t4.z;  v.w = x4.w + a*p4.w + t4.w;
            ((float4*)Xsh)[tid + k*256] = v;
        }
    }
    __syncthreads();

    int g  = tid >> 3;      // group 0..31 (one aligned 8-lane half-row)
    int sl = tid & 7;       // sub-lane: rows sl*8 .. sl*8+7
    float4 A0, A1, B0, B1;
    {
        int ca = 2*g, cb = 2*g + 1, r0 = sl*8;
        #define LDCOL(V,C,RO) V.x = Xsh[(r0+RO+0)*64+(C)]; V.y = Xsh[(r0+RO+1)*64+(C)]; \
                              V.z = Xsh[(r0+RO+2)*64+(C)]; V.w = Xsh[(r0+RO+3)*64+(C)];
        LDCOL(A0,ca,0) LDCOL(A1,ca,4)
        LDCOL(B0,cb,0) LDCOL(B1,cb,4)
        #undef LDCOL
    }
    float aa = rsum8(DOT4(A0,A0) + DOT4(A1,A1));
    float bb = rsum8(DOT4(B0,B0) + DOT4(B1,B1));

    const int total = NSWEEP * 63;
    for(int gr = 0; gr < total; ++gr){
        float cc = rsum8(DOT4(A0,B0) + DOT4(A1,B1));
        // branch-free angle, 3 transcendentals:
        // d=bb-aa; s=sqrt(d^2+4c^2); t = sgn(d)*2c/(|d|+s)
        float dd = bb - aa;
        float c2 = cc + cc;
        float s  = __builtin_amdgcn_sqrtf(__builtin_fmaf(dd, dd, c2*c2));
        float t0 = c2 * __builtin_amdgcn_rcpf(fabsf(dd) + s + 1e-30f);
        float t  = (dd < 0.f) ? -t0 : t0;
        float cs = __builtin_amdgcn_rsqf(__builtin_fmaf(t, t, 1.f));
        float sn = t * cs;
        float naN = aa - t*cc;      // rotated-A squared norm (Golub update)
        float nbN = bb + t*cc;      // rotated-B squared norm
        if(gr != total - 1){
            int par = gr & 1;
            float* MAp = P_MA(par);
            float* MBp = P_MB(par);
            // rotate & ship outgoing B first (overlap write latency with A rotation)
            float4 nb0, nb1;
            nb0.x = sn*A0.x + cs*B0.x; nb0.y = sn*A0.y + cs*B0.y;
            nb0.z = sn*A0.z + cs*B0.z; nb0.w = sn*A0.w + cs*B0.w;
            nb1.x = sn*A1.x + cs*B1.x; nb1.y = sn*A1.y + cs*B1.y;
            nb1.z = sn*A1.z + cs*B1.z; nb1.w = sn*A1.w + cs*B1.w;
            float* cbB = (g == 0) ? (MAp + 1*MCS) : (MBp + (g-1)*MCS);
            *(float4*)(cbB + sl*8)     = nb0;
            *(float4*)(cbB + sl*8 + 4) = nb1;
            if(sl == 0) cbB[64] = nbN;
            float4 na0, na1;
            na0.x = cs*A0.x - sn*B0.x; na0.y = cs*A0.y - sn*B0.y;
            na0.z = cs*A0.z - sn*B0.z; na0.w = cs*A0.w - sn*B0.w;
            na1.x = cs*A1.x - sn*B1.x; na1.y = cs*A1.y - sn*B1.y;
            na1.z = cs*A1.z - sn*B1.z; na1.w = cs*A1.w - sn*B1.w;
            if(g >= 1 && g <= 30){
                float* cbA = MAp + (g+1)*MCS;
                *(float4*)(cbA + sl*8)     = na0;
                *(float4*)(cbA + sl*8 + 4) = na1;
                if(sl == 0) cbA[64] = naN;
            }
            __syncthreads();
            float4 nA0 = na0, nA1 = na1;  float nAa = naN;   // g==0 keeps rotated A
            float4 nB0 = na0, nB1 = na1;  float nBb = naN;   // g==31: new B = rotated A
            if(g >= 1){
                const float* ra = MAp + g*MCS;
                nA0 = *(const float4*)(ra + sl*8);
                nA1 = *(const float4*)(ra + sl*8 + 4);
                nAa = ra[64];
            }
            if(g <= 30){
                const float* rb = MBp + g*MCS;
                nB0 = *(const float4*)(rb + sl*8);
                nB1 = *(const float4*)(rb + sl*8 + 4);
                nBb = rb[64];
            }
            A0 = nA0; A1 = nA1; B0 = nB0; B1 = nB1; aa = nAa; bb = nBb;
        } else {
            float4 na;
            #define ROT(Aq,Bq) na.x = cs*Aq.x - sn*Bq.x; na.y = cs*Aq.y - sn*Bq.y; \
                               na.z = cs*Aq.z - sn*Bq.z; na.w = cs*Aq.w - sn*Bq.w; \
                               Bq.x = sn*Aq.x + cs*Bq.x; Bq.y = sn*Aq.y + cs*Bq.y; \
                               Bq.z = sn*Aq.z + cs*Bq.z; Bq.w = sn*Aq.w + cs*Bq.w; Aq = na;
            ROT(A0,B0) ROT(A1,B1)
            #undef ROT
        }
    }
    // final column norms (exact, drift-free) + store W to LDS
    {
        float fa = rsum8(DOT4(A0,A0) + DOT4(A1,A1));
        float fb = rsum8(DOT4(B0,B0) + DOT4(B1,B1));
        __syncthreads();   // mailbox reads done before Wc (aliases MB) written
        float* Wc = P_WC;
        float* wa = Wc + (2*g)*MCS + sl*8;
        *(float4*)(wa)     = A0;  *(float4*)(wa + 4) = A1;
        float* wb = Wc + (2*g+1)*MCS + sl*8;
        *(float4*)(wb)     = B0;  *(float4*)(wb + 4) = B1;
        if(sl == 0){ s2[2*g] = fa; s2[2*g+1] = fb; }
    }
    __syncthreads();
    if(tid < 64){
        float v = s2[tid];
        for(int m = 32; m >= 1; m >>= 1) v = fmaxf(v, __shfl_xor(v, m, 64));
        if(tid == 0) smax_sh = sqrtf(v);
    }
    __syncthreads();
    if(tid < 64){
        float s = sqrtf(s2[tid]);
        float v = vp[0];
        float tau = 0.4f / (1.f + expf(-v));     // sigmoid(v)*COEF_GAMMA
        float thr = tau * smax_sh;
        coef3[tid] = (s > thr && s > 1e-20f) ? (s - thr) / (s*s*s) : 0.f;
    }
    __syncthreads();

    const float* Wc = P_WC;
    float* Tsh = P_TSH;
    // R1: T'[k][j] = coef3[k] * sum_r Wc[k][r] * Xsh[r][j]   (16 cols per thread)
    {
        int kk = tid >> 2;
        int j0 = (tid & 3) * 16;
        float acc[16];
        #pragma unroll
        for(int j = 0; j < 16; ++j) acc[j] = 0.f;
        for(int r = 0; r < 64; ++r){
            float wk = Wc[kk*MCS + r];
            const float* xr = Xsh + r*64 + j0;
            float4 x0 = *(const float4*)(xr);
            float4 x1 = *(const float4*)(xr + 4);
            float4 x2 = *(const float4*)(xr + 8);
            float4 x3 = *(const float4*)(xr + 12);
            acc[0]+=wk*x0.x; acc[1]+=wk*x0.y; acc[2]+=wk*x0.z; acc[3]+=wk*x0.w;
            acc[4]+=wk*x1.x; acc[5]+=wk*x1.y; acc[6]+=wk*x1.z; acc[7]+=wk*x1.w;
            acc[8]+=wk*x2.x; acc[9]+=wk*x2.y; acc[10]+=wk*x2.z; acc[11]+=wk*x2.w;
            acc[12]+=wk*x3.x; acc[13]+=wk*x3.y; acc[14]+=wk*x3.z; acc[15]+=wk*x3.w;
        }
        float c3 = coef3[kk];
        float* tr = Tsh + kk*64 + j0;
        #pragma unroll
        for(int j = 0; j < 16; ++j) tr[j] = c3 * acc[j];
    }
    __syncthreads();

    // R2: Ltmp[i][j] = sum_k Wc[k][i] * T'[k][j]; outputs   (16 cols per thread)
    {
        float neta = netap[0];
        int i  = tid >> 2;
        int j0 = (tid & 3) * 16;
        float acc[16];
        #pragma unroll
        for(int j = 0; j < 16; ++j) acc[j] = 0.f;
        for(int kk = 0; kk < 64; ++kk){
            float wik = Wc[kk*MCS + i];
            const float* tr = Tsh + kk*64 + j0;
            float4 t0 = *(const float4*)(tr);
            float4 t1 = *(const float4*)(tr + 4);
            float4 t2 = *(const float4*)(tr + 8);
            float4 t3 = *(const float4*)(tr + 12);
            acc[0]+=wik*t0.x; acc[1]+=wik*t0.y; acc[2]+=wik*t0.z; acc[3]+=wik*t0.w;
            acc[4]+=wik*t1.x; acc[5]+=wik*t1.y; acc[6]+=wik*t1.z; acc[7]+=wik*t1.w;
            acc[8]+=wik*t2.x; acc[9]+=wik*t2.y; acc[10]+=wik*t2.z; acc[11]+=wik*t2.w;
            acc[12]+=wik*t3.x; acc[13]+=wik*t3.y; acc[14]+=wik*t3.z; acc[15]+=wik*t3.w;
        }
        int n0 = i*64 + j0;
        #pragma unroll
        for(int c = 0; c < 4; ++c){
            float4 th = *(const float4*)(thP + n0 + 4*c);
            float4 lt, pt;
            lt.x = acc[4*c+0]; lt.y = acc[4*c+1]; lt.z = acc[4*c+2]; lt.w = acc[4*c+3];
            float4 xs = *(const float4*)(Xsh + n0 + 4*c);
            pt.x = th.x + neta * (xs.x - th.x - lt.x);
            pt.y = th.y + neta * (xs.y - th.y - lt.y);
            pt.z = th.z + neta * (xs.z - th.z - lt.z);
            pt.w = th.w + neta * (xs.w - th.w - lt.w);
            *(float4*)(out + n0 + 4*c)      = lt;
            *(float4*)(out + NN + n0 + 4*c) = pt;
        }
    }
}

extern "C" void kernel_launch(void* const* d_in, const int* in_sizes, int n_in,
                              void* d_out, int out_size, void* d_ws, size_t ws_size,
                              hipStream_t stream){
    const float* inp  = (const float*)d_in[0];
    const float* L    = (const float*)d_in[1];
    const int*   mask = (const int*)  d_in[2];
    const float* D    = (const float*)d_in[3];
    const float* thP  = (const float*)d_in[4];
    const float* vS   = (const float*)d_in[5];
    const float* neta = (const float*)d_in[6];
    const float* l1   = (const float*)d_in[7];
    const float* l2   = (const float*)d_in[8];
    const float* rho  = (const float*)d_in[9];
    const float* S    = (const float*)d_in[10];
    float* wf = (float*)d_ws;
    float* out = (float*)d_out;
    const bool use_bf16 = (ws_size >= WS_NEED_BF16);
    unsigned short* Dh = (unsigned short*)((char*)d_ws + DH_OFF_BYTES);

    float* Xb[2]  = { wf + OFF_X0, wf + OFF_X1 };
    float* Rb[2]  = { wf + OFF_R0, wf + OFF_R1 };
    float* Pb[2]  = { wf + OFF_P0, wf + OFF_P1 };
    float* Yb[2]  = { wf + OFF_Y0, wf + OFF_Y1 };
    float* pty[2] = { wf + OFF_PTY0, wf + OFF_PTY1 };

    if(use_bf16){
        // merged prep + iteration 0 (writes pty[0])
        k_fc<<<1024, 256, 0, stream>>>(D, Dh, inp, L, mask, thP, S,
                                       l1, l2, rho, wf, pty[0]);
        for(int j = 1; j < NITER; ++j){
            int ro = (j+1)&1, wr = j&1;
            k_step_h<<<1024, 256, 0, stream>>>(Dh, l1, l2, wf,
                Rb[ro], Pb[ro], Xb[ro], Yb[ro],
                Rb[wr], Pb[wr], Xb[wr], Yb[wr],
                pty[(j-1)&1], pty[j&1]);
        }
    } else {
        k_prep<<<16, 256, 0, stream>>>(inp, L, mask, thP, S, l2, rho, wf);
        k_step_f<<<1024, 256, 0, stream>>>(D, l1, l2, wf,
            Rb[0], Pb[0], Xb[0], Yb[0], Rb[1], Pb[1], Xb[1], Yb[0],
            pty[0], pty[0], 0);
        for(int j = 1; j < NITER; ++j){
            int ro = (j+1)&1, wr = j&1;
            k_step_f<<<1024, 256, 0, stream>>>(D, l1, l2, wf,
                Rb[ro], Pb[ro], Xb[ro], Yb[ro],
                Rb[wr], Pb[wr], Xb[wr], Yb[wr],
                pty[(j-1)&1], pty[j&1], 1);
        }
    }
    // NITER=4 -> last write parity = (NITER-1)&1 = 1
    const int lp = (NITER-1)&1;
    k_svt<<<1, 256, 0, stream>>>(thP, vS, neta, wf, Rb[lp], Pb[lp], Xb[lp],
                                 pty[lp], out);
}

// Round 9
// 280.999 us; speedup vs baseline: 1.0254x; 1.0254x over previous
//
#include <hip/hip_runtime.h>
#include <hip/hip_bf16.h>

#define NN 4096
#define NITER 4
#define NSWEEP 5
#define MCS 68     // mailbox/Wc column stride (floats); [64] holds the column's squared norm

// workspace float layout (double-buffered CG vectors INCLUDING y)
#define OFF_STS  64
#define OFF_QRHO (OFF_STS + NN)
#define OFF_DINV (OFF_QRHO + NN)
#define OFF_Y0   (OFF_DINV + NN)
#define OFF_Y1   (OFF_Y0 + NN)
#define OFF_X0   (OFF_Y1 + NN)
#define OFF_X1   (OFF_X0 + NN)
#define OFF_R0   (OFF_X1 + NN)
#define OFF_R1   (OFF_R0 + NN)
#define OFF_P0   (OFF_R1 + NN)
#define OFF_P1   (OFF_P0 + NN)
// per-block pTy partials, double-buffered by iteration parity
#define OFF_PTY0 (OFF_P1 + NN)
#define OFF_PTY1 (OFF_PTY0 + 1024)
#define DH_OFF_BYTES 196608
#define WS_NEED_BF16 (DH_OFF_BYTES + (size_t)NN * NN * 2)

typedef unsigned int uint;
__device__ inline float lo2f(uint w){ return __uint_as_float(w << 16); }
__device__ inline float hi2f(uint w){ return __uint_as_float(w & 0xffff0000u); }
__device__ inline uint f2b(float f){
    uint u = __float_as_uint(f);
    return (u + 0x7FFFu + ((u >> 16) & 1u)) >> 16;   // RNE
}
// 16-lane sum via DPP only (VALU latency, no DS pipe). Valid when the 16 lanes
// of a group are an aligned 16-lane DPP row (group g = lanes 16g..16g+15).
__device__ inline float rsum16(float x){
    int a = __builtin_amdgcn_update_dpp(0, __float_as_int(x), 0xB1, 0xF, 0xF, true);
    float s = x + __int_as_float(a);
    int b = __builtin_amdgcn_update_dpp(0, __float_as_int(s), 0x4E, 0xF, 0xF, true);
    s = s + __int_as_float(b);
    int c = __builtin_amdgcn_update_dpp(0, __float_as_int(s), 0x141, 0xF, 0xF, true);  // row_half_mirror
    s = s + __int_as_float(c);
    int d = __builtin_amdgcn_update_dpp(0, __float_as_int(s), 0x140, 0xF, 0xF, true);  // row_mirror
    s = s + __int_as_float(d);
    return s;
}

// ---------------- prep (FALLBACK PATH ONLY): StS + b + approx diag + CG init ----------------
__global__ void k_prep(const float* __restrict__ inp, const float* __restrict__ L,
                       const int*  __restrict__ mask, const float* __restrict__ thP,
                       const float* __restrict__ S,
                       const float* __restrict__ l2p, const float* __restrict__ rhop,
                       float* __restrict__ wf){
    int t = blockIdx.x * 256 + threadIdx.x;   // 4096 threads
    int r = t >> 6, c = t & 63;
    float acc = 0.f, acc2 = 0.f;
    for(int h = 0; h < 64; ++h){
        float sr = S[h*64 + r];
        float sc = S[h*64 + c];
        acc  += sr * sc;
        acc2 += sc * sc;
    }
    wf[OFF_STS + t] = acc;
    float rho = rhop[0], l2 = l2p[0];
    float q = (mask[t] != 0) ? 1.f : 0.f;
    float bi = rho * (L[t] - thP[t]) + q * inp[t];
    float dinv = 1.f / (q + rho + l2 * acc2);   // preconditioner only
    wf[OFF_QRHO + t] = q + rho;
    wf[OFF_DINV + t] = dinv;
    wf[OFF_X0 + t]   = 0.f;
    wf[OFF_R0 + t]   = bi;
    wf[OFF_P0 + t]   = bi * dinv;
}

// ---------------- per-block redundant CG scalar update (no fences needed) ----------------
// pTy of the previous iteration arrives as 1024 per-block partials; its sum is
// folded into the first shuffle-reduction tree (red[0..3]=rz, red[4..7]=pTy).
__device__ inline void cg_prologue(float* __restrict__ wf,
                                   const float* __restrict__ rold, const float* __restrict__ pold,
                                   const float* __restrict__ xold, const float* __restrict__ yold,
                                   float* __restrict__ rnew, float* __restrict__ pnew,
                                   float* __restrict__ xnew,
                                   const float* __restrict__ pty_read,
                                   float* __restrict__ psh,
                                   float* __restrict__ red){
    int tid = threadIdx.x;
    const float* dinv = wf + OFF_DINV;
    float4 r4[4], d4[4];
    float part = 0.f;
    #pragma unroll
    for(int k = 0; k < 4; ++k){
        r4[k] = ((const float4*)rold)[tid + k*256];
        d4[k] = ((const float4*)dinv)[tid + k*256];
        part += r4[k].x*r4[k].x*d4[k].x + r4[k].y*r4[k].y*d4[k].y
              + r4[k].z*r4[k].z*d4[k].z + r4[k].w*r4[k].w*d4[k].w;
    }
    float pp = pty_read[tid] + pty_read[tid+256] + pty_read[tid+512] + pty_read[tid+768];
    for(int m = 32; m >= 1; m >>= 1){
        part += __shfl_xor(part, m, 64);
        pp   += __shfl_xor(pp, m, 64);
    }
    int wave = tid >> 6, lane = tid & 63;
    if(lane == 0){ red[wave] = part; red[4+wave] = pp; }
    __syncthreads();
    float rzold = red[0] + red[1] + red[2] + red[3];
    float ptys  = red[4] + red[5] + red[6] + red[7];
    float alpha = rzold / ptys;
    float4 rn[4], zn[4];
    float part2 = 0.f;
    #pragma unroll
    for(int k = 0; k < 4; ++k){
        float4 y4 = ((const float4*)yold)[tid + k*256];
        rn[k].x = r4[k].x - alpha*y4.x;  rn[k].y = r4[k].y - alpha*y4.y;
        rn[k].z = r4[k].z - alpha*y4.z;  rn[k].w = r4[k].w - alpha*y4.w;
        zn[k].x = rn[k].x*d4[k].x;  zn[k].y = rn[k].y*d4[k].y;
        zn[k].z = rn[k].z*d4[k].z;  zn[k].w = rn[k].w*d4[k].w;
        part2 += rn[k].x*zn[k].x + rn[k].y*zn[k].y + rn[k].z*zn[k].z + rn[k].w*zn[k].w;
    }
    for(int m = 32; m >= 1; m >>= 1) part2 += __shfl_xor(part2, m, 64);
    __syncthreads();                      // all reads of red done
    if(lane == 0) red[wave] = part2;
    __syncthreads();
    float rznew = red[0] + red[1] + red[2] + red[3];
    float beta = rznew / rzold;
    bool b0 = (blockIdx.x == 0);
    #pragma unroll
    for(int k = 0; k < 4; ++k){
        float4 po = ((const float4*)pold)[tid + k*256];
        float4 pn;
        pn.x = zn[k].x + beta*po.x;  pn.y = zn[k].y + beta*po.y;
        pn.z = zn[k].z + beta*po.z;  pn.w = zn[k].w + beta*po.w;
        ((float4*)psh)[tid + k*256] = pn;
        if(b0){
            ((float4*)pnew)[tid + k*256] = pn;
            ((float4*)rnew)[tid + k*256] = rn[k];
            float4 xo = ((const float4*)xold)[tid + k*256];
            float4 xn;
            xn.x = xo.x + alpha*po.x;  xn.y = xo.y + alpha*po.y;
            xn.z = xo.z + alpha*po.z;  xn.w = xo.w + alpha*po.w;
            ((float4*)xnew)[tid + k*256] = xn;
        }
    }
    __syncthreads();
}

// ---------------- merged prep + CG step 0: fp32 D matvec + emit bf16 Dh ----------------
__launch_bounds__(256)
__global__ void k_fc(const float* __restrict__ D, unsigned short* __restrict__ Dh,
                     const float* __restrict__ inp, const float* __restrict__ L,
                     const int*  __restrict__ mask, const float* __restrict__ thP,
                     const float* __restrict__ S,
                     const float* __restrict__ l1p, const float* __restrict__ l2p,
                     const float* __restrict__ rhop,
                     float* __restrict__ wf, float* __restrict__ pty_out){
    __shared__ float psh[NN];
    __shared__ float red[8];
    __shared__ float cparts[256];
    int tid = threadIdx.x;
    int wave = tid >> 6, lane = tid & 63;
    int row = blockIdx.x * 4 + wave;
    int u = row & 63, h = row >> 6;
    float l1 = l1p[0], l2 = l2p[0], rho = rhop[0];

    // S column-norm^2 partials (for dinv): wave w covers hh = 16w..16w+15
    {
        float cp = 0.f;
        for(int hh = wave*16; hh < wave*16 + 16; ++hh){
            float sv = S[hh*64 + lane];
            cp += sv * sv;
        }
        cparts[wave*64 + lane] = cp;
    }
    // StS row u (this wave's row), element 'lane'  (S is 16KB -> L1-hot)
    float stv = 0.f;
    for(int hh = 0; hh < 64; ++hh)
        stv += S[hh*64 + u] * S[hh*64 + lane];
    if(row < 64) wf[OFF_STS + row*64 + lane] = stv;   // canonical StS (blocks 0..15)
    __syncthreads();

    // build p0 into psh (redundant per block); canonical inits from blocks 0..15
    int c = tid & 63;
    float cs4 = cparts[c] + cparts[64+c] + cparts[128+c] + cparts[192+c];
    bool canon = (blockIdx.x < 16);
    for(int k = 0; k < 16; ++k){
        int t = tid + k*256;                    // t&63 == tid&63
        float q = (mask[t] != 0) ? 1.f : 0.f;
        float bi = rho * (L[t] - thP[t]) + q * inp[t];
        float dinv = 1.f / (q + rho + l2 * cs4);
        psh[t] = bi * dinv;
        if(canon && k == (int)blockIdx.x){
            wf[OFF_QRHO + t] = q + rho;
            wf[OFF_DINV + t] = dinv;
            wf[OFF_X0 + t]   = 0.f;
            wf[OFF_R0 + t]   = bi;
            wf[OFF_P0 + t]   = bi * dinv;
        }
    }
    __syncthreads();

    // fp32 matvec + emit bf16 Dh
    const float* Drow = D + (size_t)row * NN;
    unsigned short* Dhrow = Dh + (size_t)row * NN;
    float dacc = 0.f;
    for(int j = 0; j < 16; ++j){
        int c0 = j*256 + lane*4;
        float4 dv = *(const float4*)(Drow + c0);
        float4 pa = *(const float4*)(psh + c0);
        dacc += dv.x*pa.x + dv.y*pa.y + dv.z*pa.z + dv.w*pa.w;
        uint2 o;
        o.x = f2b(dv.x) | (f2b(dv.y) << 16);
        o.y = f2b(dv.z) | (f2b(dv.w) << 16);
        *(uint2*)(Dhrow + c0) = o;
    }
    float sacc = stv * psh[h*64 + lane];
    float val = l1 * dacc + l2 * sacc;
    for(int m = 32; m >= 1; m >>= 1) val += __shfl_xor(val, m, 64);
    if(lane == 0){
        float qr = ((mask[row] != 0) ? 1.f : 0.f) + rho;   // local (canonical QRHO may race in-kernel)
        float yi = val + qr * psh[row];
        (wf + OFF_Y0)[row] = yi;
        red[wave] = yi * psh[row];
    }
    __syncthreads();
    if(tid == 0) pty_out[blockIdx.x] = red[0] + red[1] + red[2] + red[3];
}

// ---------------- CG step j>=1: prologue + y = A p (bf16 D) + pTy partial ----------------
__launch_bounds__(256)
__global__ void k_step_h(const unsigned short* __restrict__ Dh,
                         const float* __restrict__ l1p, const float* __restrict__ l2p,
                         float* __restrict__ wf,
                         const float* __restrict__ rold, const float* __restrict__ pold,
                         const float* __restrict__ xold, const float* __restrict__ yold,
                         float* __restrict__ rnew, float* __restrict__ pnew,
                         float* __restrict__ xnew, float* __restrict__ ynew,
                         const float* __restrict__ pty_read, float* __restrict__ pty_write){
    __shared__ float psh[NN];
    __shared__ float red[8];
    int tid = threadIdx.x;
    cg_prologue(wf, rold, pold, xold, yold, rnew, pnew, xnew, pty_read, psh, red);

    float l1 = l1p[0], l2 = l2p[0];
    int wave = tid >> 6, lane = tid & 63;
    int row = blockIdx.x * 4 + wave;
    int h = row >> 6, u = row & 63;
    const float* qrho = wf + OFF_QRHO;
    const float* StS  = wf + OFF_STS;

    const unsigned short* Drow = Dh + (size_t)row * NN;
    float dacc = 0.f;
    for(int j = 0; j < 8; ++j){
        int c0 = j*512 + lane*8;
        uint4 dv = *(const uint4*)(Drow + c0);
        float4 pa = *(const float4*)(psh + c0);
        float4 pb = *(const float4*)(psh + c0 + 4);
        dacc += lo2f(dv.x)*pa.x + hi2f(dv.x)*pa.y
              + lo2f(dv.y)*pa.z + hi2f(dv.y)*pa.w
              + lo2f(dv.z)*pb.x + hi2f(dv.z)*pb.y
              + lo2f(dv.w)*pb.z + hi2f(dv.w)*pb.w;
    }
    float sacc = StS[u*64 + lane] * psh[h*64 + lane];
    float val = l1 * dacc + l2 * sacc;
    for(int m = 32; m >= 1; m >>= 1) val += __shfl_xor(val, m, 64);
    if(lane == 0){
        float yi = val + qrho[row] * psh[row];
        if(ynew) ynew[row] = yi;          // last iteration's y is never consumed
        red[wave] = yi * psh[row];
    }
    __syncthreads();
    if(tid == 0) pty_write[blockIdx.x] = red[0] + red[1] + red[2] + red[3];
}

// ---------------- CG step fp32 fallback (do_pro selects prologue) ----------------
__launch_bounds__(256)
__global__ void k_step_f(const float* __restrict__ D,
                         const float* __restrict__ l1p, const float* __restrict__ l2p,
                         float* __restrict__ wf,
                         const float* __restrict__ rold, const float* __restrict__ pold,
                         const float* __restrict__ xold, const float* __restrict__ yold,
                         float* __restrict__ rnew, float* __restrict__ pnew,
                         float* __restrict__ xnew, float* __restrict__ ynew,
                         const float* __restrict__ pty_read, float* __restrict__ pty_write,
                         int do_pro){
    __shared__ float psh[NN];
    __shared__ float red[8];
    int tid = threadIdx.x;
    if(do_pro){
        cg_prologue(wf, rold, pold, xold, yold, rnew, pnew, xnew, pty_read, psh, red);
    } else {
        for(int k = 0; k < 4; ++k)
            ((float4*)psh)[tid + k*256] = ((const float4*)pold)[tid + k*256];
        __syncthreads();
    }
    float l1 = l1p[0], l2 = l2p[0];
    int wave = tid >> 6, lane = tid & 63;
    int row = blockIdx.x * 4 + wave;
    int h = row >> 6, u = row & 63;
    const float* qrho = wf + OFF_QRHO;
    const float* StS  = wf + OFF_STS;
    const float* Drow = D + (size_t)row * NN;
    float dacc = 0.f;
    for(int j = 0; j < 16; ++j){
        int c0 = j*256 + lane*4;
        float4 dv = *(const float4*)(Drow + c0);
        float4 pa = *(const float4*)(psh + c0);
        dacc += dv.x*pa.x + dv.y*pa.y + dv.z*pa.z + dv.w*pa.w;
    }
    float sacc = StS[u*64 + lane] * psh[h*64 + lane];
    float val = l1 * dacc + l2 * sacc;
    for(int m = 32; m >= 1; m >>= 1) val += __shfl_xor(val, m, 64);
    if(lane == 0){
        float yi = val + qrho[row] * psh[row];
        ynew[row] = yi;
        red[wave] = yi * psh[row];
    }
    __syncthreads();
    if(tid == 0) pty_write[blockIdx.x] = red[0] + red[1] + red[2] + red[3];
}

// ---------------- SVT: register-resident Brent-Luk Jacobi + final CG update fused ----------------
// 512 threads = 32 groups x 16 sublanes; each sublane owns 4 rows (one float4).
// R8 A/B showed this beats 256-thr (133.5 vs 128.4): the 256-thr sl*8 mailbox
// stride tripled bank conflicts and doubled the dot/rotate chain; the issue-
// contention gain didn't cover it. Keep sl*4 / 8 waves.
#define P_MA(par) (POOL + (par)*2176)
#define P_MB(par) (POOL + 4352 + (par)*2176)
#define P_XSH     (POOL + 8704)
#define P_TSH     (POOL)
#define P_WC      (POOL + 4352)
#define DOT4(u,v) ((u).x*(v).x + (u).y*(v).y + (u).z*(v).z + (u).w*(v).w)

__launch_bounds__(512)
__global__ void k_svt(const float* __restrict__ thP, const float* __restrict__ vp,
                      const float* __restrict__ netap,
                      float* __restrict__ wf,
                      const float* __restrict__ rlast, const float* __restrict__ plast,
                      const float* __restrict__ xlast,
                      const float* __restrict__ ptyp,
                      float* __restrict__ out){
    __shared__ float POOL[12800];
    __shared__ float s2[64], coef3[64];
    __shared__ float smax_sh;
    __shared__ float redv[16];
    int tid = threadIdx.x;
    float* Xsh = P_XSH;

    // fused final CG update: alpha_last = rz_last / pTy_last ; X = x + alpha*p + thP
    {
        const float* dinv = wf + OFF_DINV;
        float part = 0.f;
        #pragma unroll
        for(int k = 0; k < 2; ++k){
            float4 r4 = ((const float4*)rlast)[tid + k*512];
            float4 d4 = ((const float4*)dinv)[tid + k*512];
            part += r4.x*r4.x*d4.x + r4.y*r4.y*d4.y + r4.z*r4.z*d4.z + r4.w*r4.w*d4.w;
        }
        float pp = ptyp[tid] + ptyp[tid + 512];
        for(int m = 32; m >= 1; m >>= 1){
            part += __shfl_xor(part, m, 64);
            pp   += __shfl_xor(pp, m, 64);
        }
        if((tid & 63) == 0){ redv[tid >> 6] = part; redv[8 + (tid >> 6)] = pp; }
        __syncthreads();
        float rz = redv[0] + redv[1] + redv[2] + redv[3]
                 + redv[4] + redv[5] + redv[6] + redv[7];
        float ptys = redv[8] + redv[9] + redv[10] + redv[11]
                   + redv[12] + redv[13] + redv[14] + redv[15];
        float a = rz / ptys;
        #pragma unroll
        for(int k = 0; k < 2; ++k){
            float4 x4 = ((const float4*)xlast)[tid + k*512];
            float4 p4 = ((const float4*)plast)[tid + k*512];
            float4 t4 = ((const float4*)thP)[tid + k*512];
            float4 v;
            v.x = x4.x + a*p4.x + t4.x;  v.y = x4.y + a*p4.y + t4.y;
            v.z = x4.z + a*p4.z + t4.z;  v.w = x4.w + a*p4.w + t4.w;
            ((float4*)Xsh)[tid + k*512] = v;
        }
    }
    __syncthreads();

    int g  = tid >> 4;      // group 0..31 (one aligned 16-lane DPP row)
    int sl = tid & 15;      // sub-lane: rows sl*4 .. sl*4+3
    float4 A, B;
    {
        int ca = 2*g, cb = 2*g + 1, r0 = sl*4;
        A.x = Xsh[(r0+0)*64+ca]; A.y = Xsh[(r0+1)*64+ca];
        A.z = Xsh[(r0+2)*64+ca]; A.w = Xsh[(r0+3)*64+ca];
        B.x = Xsh[(r0+0)*64+cb]; B.y = Xsh[(r0+1)*64+cb];
        B.z = Xsh[(r0+2)*64+cb]; B.w = Xsh[(r0+3)*64+cb];
    }
    float aa = rsum16(DOT4(A,A));
    float bb = rsum16(DOT4(B,B));

    const int total = NSWEEP * 63;
    for(int gr = 0; gr < total; ++gr){
        float cc = rsum16(DOT4(A,B));
        // branch-free angle, 3 transcendentals:
        // d=bb-aa; s=sqrt(d^2+4c^2); t = sgn(d)*2c/(|d|+s)
        float dd = bb - aa;
        float c2 = cc + cc;
        float s  = __builtin_amdgcn_sqrtf(__builtin_fmaf(dd, dd, c2*c2));
        float t0 = c2 * __builtin_amdgcn_rcpf(fabsf(dd) + s + 1e-30f);
        float t  = (dd < 0.f) ? -t0 : t0;
        float cs = __builtin_amdgcn_rsqf(__builtin_fmaf(t, t, 1.f));
        float sn = t * cs;
        float naN = aa - t*cc;      // rotated-A squared norm (Golub update)
        float nbN = bb + t*cc;      // rotated-B squared norm
        if(gr != total - 1){
            int par = gr & 1;
            float* MAp = P_MA(par);
            float* MBp = P_MB(par);
            // rotate & ship outgoing B first (overlap write latency with A rotation)
            float4 nb;
            nb.x = sn*A.x + cs*B.x; nb.y = sn*A.y + cs*B.y;
            nb.z = sn*A.z + cs*B.z; nb.w = sn*A.w + cs*B.w;
            float* cbB = (g == 0) ? (MAp + 1*MCS) : (MBp + (g-1)*MCS);
            *(float4*)(cbB + sl*4) = nb;
            if(sl == 0) cbB[64] = nbN;
            float4 na;
            na.x = cs*A.x - sn*B.x; na.y = cs*A.y - sn*B.y;
            na.z = cs*A.z - sn*B.z; na.w = cs*A.w - sn*B.w;
            if(g >= 1 && g <= 30){
                float* cbA = MAp + (g+1)*MCS;
                *(float4*)(cbA + sl*4) = na;
                if(sl == 0) cbA[64] = naN;
            }
            __syncthreads();
            float4 nA = na;  float nAa = naN;   // g==0 keeps rotated A
            float4 nB = na;  float nBb = naN;   // g==31: new B = rotated A
            if(g >= 1){
                const float* ra = MAp + g*MCS;
                nA = *(const float4*)(ra + sl*4);
                nAa = ra[64];
            }
            if(g <= 30){
                const float* rb = MBp + g*MCS;
                nB = *(const float4*)(rb + sl*4);
                nBb = rb[64];
            }
            A = nA; B = nB; aa = nAa; bb = nBb;
        } else {
            float4 na;
            na.x = cs*A.x - sn*B.x; na.y = cs*A.y - sn*B.y;
            na.z = cs*A.z - sn*B.z; na.w = cs*A.w - sn*B.w;
            float4 nbf;
            nbf.x = sn*A.x + cs*B.x; nbf.y = sn*A.y + cs*B.y;
            nbf.z = sn*A.z + cs*B.z; nbf.w = sn*A.w + cs*B.w;
            A = na; B = nbf;
        }
    }
    // final column norms (exact, drift-free) + store W to LDS
    {
        float fa = rsum16(DOT4(A,A));
        float fb = rsum16(DOT4(B,B));
        __syncthreads();   // mailbox reads done before Wc (aliases MB) written
        float* Wc = P_WC;
        *(float4*)(Wc + (2*g)*MCS + sl*4)   = A;
        *(float4*)(Wc + (2*g+1)*MCS + sl*4) = B;
        if(sl == 0){ s2[2*g] = fa; s2[2*g+1] = fb; }
    }
    __syncthreads();
    if(tid < 64){
        float v = s2[tid];
        for(int m = 32; m >= 1; m >>= 1) v = fmaxf(v, __shfl_xor(v, m, 64));
        if(tid == 0) smax_sh = sqrtf(v);
    }
    __syncthreads();
    if(tid < 64){
        float s = sqrtf(s2[tid]);
        float v = vp[0];
        float tau = 0.4f / (1.f + expf(-v));     // sigmoid(v)*COEF_GAMMA
        float thr = tau * smax_sh;
        coef3[tid] = (s > thr && s > 1e-20f) ? (s - thr) / (s*s*s) : 0.f;
    }
    __syncthreads();

    const float* Wc = P_WC;
    float* Tsh = P_TSH;
    // R1: T'[k][j] = coef3[k] * sum_r Wc[k][r] * Xsh[r][j]   (8 cols per thread)
    {
        int kk = tid >> 3;
        int j0 = (tid & 7) * 8;
        float acc[8];
        #pragma unroll
        for(int j = 0; j < 8; ++j) acc[j] = 0.f;
        for(int r = 0; r < 64; ++r){
            float wk = Wc[kk*MCS + r];
            const float* xr = Xsh + r*64 + j0;
            float4 x0 = *(const float4*)(xr);
            float4 x1 = *(const float4*)(xr + 4);
            acc[0]+=wk*x0.x; acc[1]+=wk*x0.y; acc[2]+=wk*x0.z; acc[3]+=wk*x0.w;
            acc[4]+=wk*x1.x; acc[5]+=wk*x1.y; acc[6]+=wk*x1.z; acc[7]+=wk*x1.w;
        }
        float c3 = coef3[kk];
        float* tr = Tsh + kk*64 + j0;
        float4 t0, t1;
        t0.x = c3*acc[0]; t0.y = c3*acc[1]; t0.z = c3*acc[2]; t0.w = c3*acc[3];
        t1.x = c3*acc[4]; t1.y = c3*acc[5]; t1.z = c3*acc[6]; t1.w = c3*acc[7];
        *(float4*)(tr)     = t0;
        *(float4*)(tr + 4) = t1;
    }
    __syncthreads();

    // R2: Ltmp[i][j] = sum_k Wc[k][i] * T'[k][j]; outputs   (8 cols per thread)
    {
        float neta = netap[0];
        int i  = tid >> 3;
        int j0 = (tid & 7) * 8;
        float acc[8];
        #pragma unroll
        for(int j = 0; j < 8; ++j) acc[j] = 0.f;
        for(int kk = 0; kk < 64; ++kk){
            float wik = Wc[kk*MCS + i];
            const float* tr = Tsh + kk*64 + j0;
            float4 t0 = *(const float4*)(tr);
            float4 t1 = *(const float4*)(tr + 4);
            acc[0]+=wik*t0.x; acc[1]+=wik*t0.y; acc[2]+=wik*t0.z; acc[3]+=wik*t0.w;
            acc[4]+=wik*t1.x; acc[5]+=wik*t1.y; acc[6]+=wik*t1.z; acc[7]+=wik*t1.w;
        }
        int n0 = i*64 + j0;
        #pragma unroll
        for(int c = 0; c < 2; ++c){
            float4 th = *(const float4*)(thP + n0 + 4*c);
            float4 lt, pt;
            lt.x = acc[4*c+0]; lt.y = acc[4*c+1]; lt.z = acc[4*c+2]; lt.w = acc[4*c+3];
            float4 xs = *(const float4*)(Xsh + n0 + 4*c);
            pt.x = th.x + neta * (xs.x - th.x - lt.x);
            pt.y = th.y + neta * (xs.y - th.y - lt.y);
            pt.z = th.z + neta * (xs.z - th.z - lt.z);
            pt.w = th.w + neta * (xs.w - th.w - lt.w);
            *(float4*)(out + n0 + 4*c)      = lt;
            *(float4*)(out + NN + n0 + 4*c) = pt;
        }
    }
}

extern "C" void kernel_launch(void* const* d_in, const int* in_sizes, int n_in,
                              void* d_out, int out_size, void* d_ws, size_t ws_size,
                              hipStream_t stream){
    const float* inp  = (const float*)d_in[0];
    const float* L    = (const float*)d_in[1];
    const int*   mask = (const int*)  d_in[2];
    const float* D    = (const float*)d_in[3];
    const float* thP  = (const float*)d_in[4];
    const float* vS   = (const float*)d_in[5];
    const float* neta = (const float*)d_in[6];
    const float* l1   = (const float*)d_in[7];
    const float* l2   = (const float*)d_in[8];
    const float* rho  = (const float*)d_in[9];
    const float* S    = (const float*)d_in[10];
    float* wf = (float*)d_ws;
    float* out = (float*)d_out;
    const bool use_bf16 = (ws_size >= WS_NEED_BF16);
    unsigned short* Dh = (unsigned short*)((char*)d_ws + DH_OFF_BYTES);

    float* Xb[2]  = { wf + OFF_X0, wf + OFF_X1 };
    float* Rb[2]  = { wf + OFF_R0, wf + OFF_R1 };
    float* Pb[2]  = { wf + OFF_P0, wf + OFF_P1 };
    float* Yb[2]  = { wf + OFF_Y0, wf + OFF_Y1 };
    float* pty[2] = { wf + OFF_PTY0, wf + OFF_PTY1 };

    if(use_bf16){
        // merged prep + iteration 0 (writes pty[0])
        k_fc<<<1024, 256, 0, stream>>>(D, Dh, inp, L, mask, thP, S,
                                       l1, l2, rho, wf, pty[0]);
        for(int j = 1; j < NITER; ++j){
            int ro = (j+1)&1, wr = j&1;
            k_step_h<<<1024, 256, 0, stream>>>(Dh, l1, l2, wf,
                Rb[ro], Pb[ro], Xb[ro], Yb[ro],
                Rb[wr], Pb[wr], Xb[wr],
                (j < NITER-1) ? Yb[wr] : (float*)nullptr,   // last y unused
                pty[(j-1)&1], pty[j&1]);
        }
    } else {
        k_prep<<<16, 256, 0, stream>>>(inp, L, mask, thP, S, l2, rho, wf);
        k_step_f<<<1024, 256, 0, stream>>>(D, l1, l2, wf,
            Rb[0], Pb[0], Xb[0], Yb[0], Rb[1], Pb[1], Xb[1], Yb[0],
            pty[0], pty[0], 0);
        for(int j = 1; j < NITER; ++j){
            int ro = (j+1)&1, wr = j&1;
            k_step_f<<<1024, 256, 0, stream>>>(D, l1, l2, wf,
                Rb[ro], Pb[ro], Xb[ro], Yb[ro],
                Rb[wr], Pb[wr], Xb[wr], Yb[wr],
                pty[(j-1)&1], pty[j&1], 1);
        }
    }
    // NITER=4 -> last write parity = (NITER-1)&1 = 1
    const int lp = (NITER-1)&1;
    k_svt<<<1, 512, 0, stream>>>(thP, vS, neta, wf, Rb[lp], Pb[lp], Xb[lp],
                                 pty[lp], out);
}

// Round 10
// 273.482 us; speedup vs baseline: 1.0536x; 1.0275x over previous
//
#include <hip/hip_runtime.h>
#include <hip/hip_bf16.h>

#define NN 4096
#define NITER 3    // ablation R10: CG truncation after 3 iters est. ~1e-2, near the
                   // bf16-D floor (2^-7) that has pinned absmax all session. 4->3
                   // removes one matvec dispatch + one ~28us boundary (~37us).
#define NSWEEP 5
#define MCS 68     // mailbox/Wc column stride (floats); [64] holds the column's squared norm

// workspace float layout (double-buffered CG vectors INCLUDING y)
#define OFF_STS  64
#define OFF_QRHO (OFF_STS + NN)
#define OFF_DINV (OFF_QRHO + NN)
#define OFF_Y0   (OFF_DINV + NN)
#define OFF_Y1   (OFF_Y0 + NN)
#define OFF_X0   (OFF_Y1 + NN)
#define OFF_X1   (OFF_X0 + NN)
#define OFF_R0   (OFF_X1 + NN)
#define OFF_R1   (OFF_R0 + NN)
#define OFF_P0   (OFF_R1 + NN)
#define OFF_P1   (OFF_P0 + NN)
// per-block pTy partials, double-buffered by iteration parity
#define OFF_PTY0 (OFF_P1 + NN)
#define OFF_PTY1 (OFF_PTY0 + 1024)
#define DH_OFF_BYTES 196608
#define WS_NEED_BF16 (DH_OFF_BYTES + (size_t)NN * NN * 2)

typedef unsigned int uint;
__device__ inline float lo2f(uint w){ return __uint_as_float(w << 16); }
__device__ inline float hi2f(uint w){ return __uint_as_float(w & 0xffff0000u); }
__device__ inline uint f2b(float f){
    uint u = __float_as_uint(f);
    return (u + 0x7FFFu + ((u >> 16) & 1u)) >> 16;   // RNE
}
// 16-lane sum via DPP only (VALU latency, no DS pipe). Valid when the 16 lanes
// of a group are an aligned 16-lane DPP row (group g = lanes 16g..16g+15).
__device__ inline float rsum16(float x){
    int a = __builtin_amdgcn_update_dpp(0, __float_as_int(x), 0xB1, 0xF, 0xF, true);
    float s = x + __int_as_float(a);
    int b = __builtin_amdgcn_update_dpp(0, __float_as_int(s), 0x4E, 0xF, 0xF, true);
    s = s + __int_as_float(b);
    int c = __builtin_amdgcn_update_dpp(0, __float_as_int(s), 0x141, 0xF, 0xF, true);  // row_half_mirror
    s = s + __int_as_float(c);
    int d = __builtin_amdgcn_update_dpp(0, __float_as_int(s), 0x140, 0xF, 0xF, true);  // row_mirror
    s = s + __int_as_float(d);
    return s;
}

// ---------------- prep (FALLBACK PATH ONLY): StS + b + approx diag + CG init ----------------
__global__ void k_prep(const float* __restrict__ inp, const float* __restrict__ L,
                       const int*  __restrict__ mask, const float* __restrict__ thP,
                       const float* __restrict__ S,
                       const float* __restrict__ l2p, const float* __restrict__ rhop,
                       float* __restrict__ wf){
    int t = blockIdx.x * 256 + threadIdx.x;   // 4096 threads
    int r = t >> 6, c = t & 63;
    float acc = 0.f, acc2 = 0.f;
    for(int h = 0; h < 64; ++h){
        float sr = S[h*64 + r];
        float sc = S[h*64 + c];
        acc  += sr * sc;
        acc2 += sc * sc;
    }
    wf[OFF_STS + t] = acc;
    float rho = rhop[0], l2 = l2p[0];
    float q = (mask[t] != 0) ? 1.f : 0.f;
    float bi = rho * (L[t] - thP[t]) + q * inp[t];
    float dinv = 1.f / (q + rho + l2 * acc2);   // preconditioner only
    wf[OFF_QRHO + t] = q + rho;
    wf[OFF_DINV + t] = dinv;
    wf[OFF_X0 + t]   = 0.f;
    wf[OFF_R0 + t]   = bi;
    wf[OFF_P0 + t]   = bi * dinv;
}

// ---------------- per-block redundant CG scalar update (no fences needed) ----------------
// pTy of the previous iteration arrives as 1024 per-block partials; its sum is
// folded into the first shuffle-reduction tree (red[0..3]=rz, red[4..7]=pTy).
__device__ inline void cg_prologue(float* __restrict__ wf,
                                   const float* __restrict__ rold, const float* __restrict__ pold,
                                   const float* __restrict__ xold, const float* __restrict__ yold,
                                   float* __restrict__ rnew, float* __restrict__ pnew,
                                   float* __restrict__ xnew,
                                   const float* __restrict__ pty_read,
                                   float* __restrict__ psh,
                                   float* __restrict__ red){
    int tid = threadIdx.x;
    const float* dinv = wf + OFF_DINV;
    float4 r4[4], d4[4];
    float part = 0.f;
    #pragma unroll
    for(int k = 0; k < 4; ++k){
        r4[k] = ((const float4*)rold)[tid + k*256];
        d4[k] = ((const float4*)dinv)[tid + k*256];
        part += r4[k].x*r4[k].x*d4[k].x + r4[k].y*r4[k].y*d4[k].y
              + r4[k].z*r4[k].z*d4[k].z + r4[k].w*r4[k].w*d4[k].w;
    }
    float pp = pty_read[tid] + pty_read[tid+256] + pty_read[tid+512] + pty_read[tid+768];
    for(int m = 32; m >= 1; m >>= 1){
        part += __shfl_xor(part, m, 64);
        pp   += __shfl_xor(pp, m, 64);
    }
    int wave = tid >> 6, lane = tid & 63;
    if(lane == 0){ red[wave] = part; red[4+wave] = pp; }
    __syncthreads();
    float rzold = red[0] + red[1] + red[2] + red[3];
    float ptys  = red[4] + red[5] + red[6] + red[7];
    float alpha = rzold / ptys;
    float4 rn[4], zn[4];
    float part2 = 0.f;
    #pragma unroll
    for(int k = 0; k < 4; ++k){
        float4 y4 = ((const float4*)yold)[tid + k*256];
        rn[k].x = r4[k].x - alpha*y4.x;  rn[k].y = r4[k].y - alpha*y4.y;
        rn[k].z = r4[k].z - alpha*y4.z;  rn[k].w = r4[k].w - alpha*y4.w;
        zn[k].x = rn[k].x*d4[k].x;  zn[k].y = rn[k].y*d4[k].y;
        zn[k].z = rn[k].z*d4[k].z;  zn[k].w = rn[k].w*d4[k].w;
        part2 += rn[k].x*zn[k].x + rn[k].y*zn[k].y + rn[k].z*zn[k].z + rn[k].w*zn[k].w;
    }
    for(int m = 32; m >= 1; m >>= 1) part2 += __shfl_xor(part2, m, 64);
    __syncthreads();                      // all reads of red done
    if(lane == 0) red[wave] = part2;
    __syncthreads();
    float rznew = red[0] + red[1] + red[2] + red[3];
    float beta = rznew / rzold;
    bool b0 = (blockIdx.x == 0);
    #pragma unroll
    for(int k = 0; k < 4; ++k){
        float4 po = ((const float4*)pold)[tid + k*256];
        float4 pn;
        pn.x = zn[k].x + beta*po.x;  pn.y = zn[k].y + beta*po.y;
        pn.z = zn[k].z + beta*po.z;  pn.w = zn[k].w + beta*po.w;
        ((float4*)psh)[tid + k*256] = pn;
        if(b0){
            ((float4*)pnew)[tid + k*256] = pn;
            ((float4*)rnew)[tid + k*256] = rn[k];
            float4 xo = ((const float4*)xold)[tid + k*256];
            float4 xn;
            xn.x = xo.x + alpha*po.x;  xn.y = xo.y + alpha*po.y;
            xn.z = xo.z + alpha*po.z;  xn.w = xo.w + alpha*po.w;
            ((float4*)xnew)[tid + k*256] = xn;
        }
    }
    __syncthreads();
}

// ---------------- merged prep + CG step 0: fp32 D matvec + emit bf16 Dh ----------------
__launch_bounds__(256)
__global__ void k_fc(const float* __restrict__ D, unsigned short* __restrict__ Dh,
                     const float* __restrict__ inp, const float* __restrict__ L,
                     const int*  __restrict__ mask, const float* __restrict__ thP,
                     const float* __restrict__ S,
                     const float* __restrict__ l1p, const float* __restrict__ l2p,
                     const float* __restrict__ rhop,
                     float* __restrict__ wf, float* __restrict__ pty_out){
    __shared__ float psh[NN];
    __shared__ float red[8];
    __shared__ float cparts[256];
    int tid = threadIdx.x;
    int wave = tid >> 6, lane = tid & 63;
    int row = blockIdx.x * 4 + wave;
    int u = row & 63, h = row >> 6;
    float l1 = l1p[0], l2 = l2p[0], rho = rhop[0];

    // S column-norm^2 partials (for dinv): wave w covers hh = 16w..16w+15
    {
        float cp = 0.f;
        for(int hh = wave*16; hh < wave*16 + 16; ++hh){
            float sv = S[hh*64 + lane];
            cp += sv * sv;
        }
        cparts[wave*64 + lane] = cp;
    }
    // StS row u (this wave's row), element 'lane'  (S is 16KB -> L1-hot)
    float stv = 0.f;
    for(int hh = 0; hh < 64; ++hh)
        stv += S[hh*64 + u] * S[hh*64 + lane];
    if(row < 64) wf[OFF_STS + row*64 + lane] = stv;   // canonical StS (blocks 0..15)
    __syncthreads();

    // build p0 into psh (redundant per block); canonical inits from blocks 0..15
    int c = tid & 63;
    float cs4 = cparts[c] + cparts[64+c] + cparts[128+c] + cparts[192+c];
    bool canon = (blockIdx.x < 16);
    for(int k = 0; k < 16; ++k){
        int t = tid + k*256;                    // t&63 == tid&63
        float q = (mask[t] != 0) ? 1.f : 0.f;
        float bi = rho * (L[t] - thP[t]) + q * inp[t];
        float dinv = 1.f / (q + rho + l2 * cs4);
        psh[t] = bi * dinv;
        if(canon && k == (int)blockIdx.x){
            wf[OFF_QRHO + t] = q + rho;
            wf[OFF_DINV + t] = dinv;
            wf[OFF_X0 + t]   = 0.f;
            wf[OFF_R0 + t]   = bi;
            wf[OFF_P0 + t]   = bi * dinv;
        }
    }
    __syncthreads();

    // fp32 matvec + emit bf16 Dh
    const float* Drow = D + (size_t)row * NN;
    unsigned short* Dhrow = Dh + (size_t)row * NN;
    float dacc = 0.f;
    for(int j = 0; j < 16; ++j){
        int c0 = j*256 + lane*4;
        float4 dv = *(const float4*)(Drow + c0);
        float4 pa = *(const float4*)(psh + c0);
        dacc += dv.x*pa.x + dv.y*pa.y + dv.z*pa.z + dv.w*pa.w;
        uint2 o;
        o.x = f2b(dv.x) | (f2b(dv.y) << 16);
        o.y = f2b(dv.z) | (f2b(dv.w) << 16);
        *(uint2*)(Dhrow + c0) = o;
    }
    float sacc = stv * psh[h*64 + lane];
    float val = l1 * dacc + l2 * sacc;
    for(int m = 32; m >= 1; m >>= 1) val += __shfl_xor(val, m, 64);
    if(lane == 0){
        float qr = ((mask[row] != 0) ? 1.f : 0.f) + rho;   // local (canonical QRHO may race in-kernel)
        float yi = val + qr * psh[row];
        (wf + OFF_Y0)[row] = yi;
        red[wave] = yi * psh[row];
    }
    __syncthreads();
    if(tid == 0) pty_out[blockIdx.x] = red[0] + red[1] + red[2] + red[3];
}

// ---------------- CG step j>=1: prologue + y = A p (bf16 D) + pTy partial ----------------
__launch_bounds__(256)
__global__ void k_step_h(const unsigned short* __restrict__ Dh,
                         const float* __restrict__ l1p, const float* __restrict__ l2p,
                         float* __restrict__ wf,
                         const float* __restrict__ rold, const float* __restrict__ pold,
                         const float* __restrict__ xold, const float* __restrict__ yold,
                         float* __restrict__ rnew, float* __restrict__ pnew,
                         float* __restrict__ xnew, float* __restrict__ ynew,
                         const float* __restrict__ pty_read, float* __restrict__ pty_write){
    __shared__ float psh[NN];
    __shared__ float red[8];
    int tid = threadIdx.x;
    cg_prologue(wf, rold, pold, xold, yold, rnew, pnew, xnew, pty_read, psh, red);

    float l1 = l1p[0], l2 = l2p[0];
    int wave = tid >> 6, lane = tid & 63;
    int row = blockIdx.x * 4 + wave;
    int h = row >> 6, u = row & 63;
    const float* qrho = wf + OFF_QRHO;
    const float* StS  = wf + OFF_STS;

    const unsigned short* Drow = Dh + (size_t)row * NN;
    float dacc = 0.f;
    for(int j = 0; j < 8; ++j){
        int c0 = j*512 + lane*8;
        uint4 dv = *(const uint4*)(Drow + c0);
        float4 pa = *(const float4*)(psh + c0);
        float4 pb = *(const float4*)(psh + c0 + 4);
        dacc += lo2f(dv.x)*pa.x + hi2f(dv.x)*pa.y
              + lo2f(dv.y)*pa.z + hi2f(dv.y)*pa.w
              + lo2f(dv.z)*pb.x + hi2f(dv.z)*pb.y
              + lo2f(dv.w)*pb.z + hi2f(dv.w)*pb.w;
    }
    float sacc = StS[u*64 + lane] * psh[h*64 + lane];
    float val = l1 * dacc + l2 * sacc;
    for(int m = 32; m >= 1; m >>= 1) val += __shfl_xor(val, m, 64);
    if(lane == 0){
        float yi = val + qrho[row] * psh[row];
        if(ynew) ynew[row] = yi;          // last iteration's y is never consumed
        red[wave] = yi * psh[row];
    }
    __syncthreads();
    if(tid == 0) pty_write[blockIdx.x] = red[0] + red[1] + red[2] + red[3];
}

// ---------------- CG step fp32 fallback (do_pro selects prologue) ----------------
__launch_bounds__(256)
__global__ void k_step_f(const float* __restrict__ D,
                         const float* __restrict__ l1p, const float* __restrict__ l2p,
                         float* __restrict__ wf,
                         const float* __restrict__ rold, const float* __restrict__ pold,
                         const float* __restrict__ xold, const float* __restrict__ yold,
                         float* __restrict__ rnew, float* __restrict__ pnew,
                         float* __restrict__ xnew, float* __restrict__ ynew,
                         const float* __restrict__ pty_read, float* __restrict__ pty_write,
                         int do_pro){
    __shared__ float psh[NN];
    __shared__ float red[8];
    int tid = threadIdx.x;
    if(do_pro){
        cg_prologue(wf, rold, pold, xold, yold, rnew, pnew, xnew, pty_read, psh, red);
    } else {
        for(int k = 0; k < 4; ++k)
            ((float4*)psh)[tid + k*256] = ((const float4*)pold)[tid + k*256];
        __syncthreads();
    }
    float l1 = l1p[0], l2 = l2p[0];
    int wave = tid >> 6, lane = tid & 63;
    int row = blockIdx.x * 4 + wave;
    int h = row >> 6, u = row & 63;
    const float* qrho = wf + OFF_QRHO;
    const float* StS  = wf + OFF_STS;
    const float* Drow = D + (size_t)row * NN;
    float dacc = 0.f;
    for(int j = 0; j < 16; ++j){
        int c0 = j*256 + lane*4;
        float4 dv = *(const float4*)(Drow + c0);
        float4 pa = *(const float4*)(psh + c0);
        dacc += dv.x*pa.x + dv.y*pa.y + dv.z*pa.z + dv.w*pa.w;
    }
    float sacc = StS[u*64 + lane] * psh[h*64 + lane];
    float val = l1 * dacc + l2 * sacc;
    for(int m = 32; m >= 1; m >>= 1) val += __shfl_xor(val, m, 64);
    if(lane == 0){
        float yi = val + qrho[row] * psh[row];
        ynew[row] = yi;
        red[wave] = yi * psh[row];
    }
    __syncthreads();
    if(tid == 0) pty_write[blockIdx.x] = red[0] + red[1] + red[2] + red[3];
}

// ---------------- SVT: register-resident Brent-Luk Jacobi + final CG update fused ----------------
// 512 threads = 32 groups x 16 sublanes; each sublane owns 4 rows (one float4).
// R8 A/B showed this beats 256-thr (133.5 vs 128.4): the 256-thr sl*8 mailbox
// stride tripled bank conflicts and doubled the dot/rotate chain; the issue-
// contention gain didn't cover it. Keep sl*4 / 8 waves.
#define P_MA(par) (POOL + (par)*2176)
#define P_MB(par) (POOL + 4352 + (par)*2176)
#define P_XSH     (POOL + 8704)
#define P_TSH     (POOL)
#define P_WC      (POOL + 4352)
#define DOT4(u,v) ((u).x*(v).x + (u).y*(v).y + (u).z*(v).z + (u).w*(v).w)

__launch_bounds__(512)
__global__ void k_svt(const float* __restrict__ thP, const float* __restrict__ vp,
                      const float* __restrict__ netap,
                      float* __restrict__ wf,
                      const float* __restrict__ rlast, const float* __restrict__ plast,
                      const float* __restrict__ xlast,
                      const float* __restrict__ ptyp,
                      float* __restrict__ out){
    __shared__ float POOL[12800];
    __shared__ float s2[64], coef3[64];
    __shared__ float smax_sh;
    __shared__ float redv[16];
    int tid = threadIdx.x;
    float* Xsh = P_XSH;

    // fused final CG update: alpha_last = rz_last / pTy_last ; X = x + alpha*p + thP
    {
        const float* dinv = wf + OFF_DINV;
        float part = 0.f;
        #pragma unroll
        for(int k = 0; k < 2; ++k){
            float4 r4 = ((const float4*)rlast)[tid + k*512];
            float4 d4 = ((const float4*)dinv)[tid + k*512];
            part += r4.x*r4.x*d4.x + r4.y*r4.y*d4.y + r4.z*r4.z*d4.z + r4.w*r4.w*d4.w;
        }
        float pp = ptyp[tid] + ptyp[tid + 512];
        for(int m = 32; m >= 1; m >>= 1){
            part += __shfl_xor(part, m, 64);
            pp   += __shfl_xor(pp, m, 64);
        }
        if((tid & 63) == 0){ redv[tid >> 6] = part; redv[8 + (tid >> 6)] = pp; }
        __syncthreads();
        float rz = redv[0] + redv[1] + redv[2] + redv[3]
                 + redv[4] + redv[5] + redv[6] + redv[7];
        float ptys = redv[8] + redv[9] + redv[10] + redv[11]
                   + redv[12] + redv[13] + redv[14] + redv[15];
        float a = rz / ptys;
        #pragma unroll
        for(int k = 0; k < 2; ++k){
            float4 x4 = ((const float4*)xlast)[tid + k*512];
            float4 p4 = ((const float4*)plast)[tid + k*512];
            float4 t4 = ((const float4*)thP)[tid + k*512];
            float4 v;
            v.x = x4.x + a*p4.x + t4.x;  v.y = x4.y + a*p4.y + t4.y;
            v.z = x4.z + a*p4.z + t4.z;  v.w = x4.w + a*p4.w + t4.w;
            ((float4*)Xsh)[tid + k*512] = v;
        }
    }
    __syncthreads();

    int g  = tid >> 4;      // group 0..31 (one aligned 16-lane DPP row)
    int sl = tid & 15;      // sub-lane: rows sl*4 .. sl*4+3
    float4 A, B;
    {
        int ca = 2*g, cb = 2*g + 1, r0 = sl*4;
        A.x = Xsh[(r0+0)*64+ca]; A.y = Xsh[(r0+1)*64+ca];
        A.z = Xsh[(r0+2)*64+ca]; A.w = Xsh[(r0+3)*64+ca];
        B.x = Xsh[(r0+0)*64+cb]; B.y = Xsh[(r0+1)*64+cb];
        B.z = Xsh[(r0+2)*64+cb]; B.w = Xsh[(r0+3)*64+cb];
    }
    float aa = rsum16(DOT4(A,A));
    float bb = rsum16(DOT4(B,B));

    const int total = NSWEEP * 63;
    for(int gr = 0; gr < total; ++gr){
        float cc = rsum16(DOT4(A,B));
        // branch-free angle, 3 transcendentals:
        // d=bb-aa; s=sqrt(d^2+4c^2); t = sgn(d)*2c/(|d|+s)
        float dd = bb - aa;
        float c2 = cc + cc;
        float s  = __builtin_amdgcn_sqrtf(__builtin_fmaf(dd, dd, c2*c2));
        float t0 = c2 * __builtin_amdgcn_rcpf(fabsf(dd) + s + 1e-30f);
        float t  = (dd < 0.f) ? -t0 : t0;
        float cs = __builtin_amdgcn_rsqf(__builtin_fmaf(t, t, 1.f));
        float sn = t * cs;
        float naN = aa - t*cc;      // rotated-A squared norm (Golub update)
        float nbN = bb + t*cc;      // rotated-B squared norm
        if(gr != total - 1){
            int par = gr & 1;
            float* MAp = P_MA(par);
            float* MBp = P_MB(par);
            // rotate & ship outgoing B first (overlap write latency with A rotation)
            float4 nb;
            nb.x = sn*A.x + cs*B.x; nb.y = sn*A.y + cs*B.y;
            nb.z = sn*A.z + cs*B.z; nb.w = sn*A.w + cs*B.w;
            float* cbB = (g == 0) ? (MAp + 1*MCS) : (MBp + (g-1)*MCS);
            *(float4*)(cbB + sl*4) = nb;
            if(sl == 0) cbB[64] = nbN;
            float4 na;
            na.x = cs*A.x - sn*B.x; na.y = cs*A.y - sn*B.y;
            na.z = cs*A.z - sn*B.z; na.w = cs*A.w - sn*B.w;
            if(g >= 1 && g <= 30){
                float* cbA = MAp + (g+1)*MCS;
                *(float4*)(cbA + sl*4) = na;
                if(sl == 0) cbA[64] = naN;
            }
            __syncthreads();
            float4 nA = na;  float nAa = naN;   // g==0 keeps rotated A
            float4 nB = na;  float nBb = naN;   // g==31: new B = rotated A
            if(g >= 1){
                const float* ra = MAp + g*MCS;
                nA = *(const float4*)(ra + sl*4);
                nAa = ra[64];
            }
            if(g <= 30){
                const float* rb = MBp + g*MCS;
                nB = *(const float4*)(rb + sl*4);
                nBb = rb[64];
            }
            A = nA; B = nB; aa = nAa; bb = nBb;
        } else {
            float4 na;
            na.x = cs*A.x - sn*B.x; na.y = cs*A.y - sn*B.y;
            na.z = cs*A.z - sn*B.z; na.w = cs*A.w - sn*B.w;
            float4 nbf;
            nbf.x = sn*A.x + cs*B.x; nbf.y = sn*A.y + cs*B.y;
            nbf.z = sn*A.z + cs*B.z; nbf.w = sn*A.w + cs*B.w;
            A = na; B = nbf;
        }
    }
    // final column norms (exact, drift-free) + store W to LDS
    {
        float fa = rsum16(DOT4(A,A));
        float fb = rsum16(DOT4(B,B));
        __syncthreads();   // mailbox reads done before Wc (aliases MB) written
        float* Wc = P_WC;
        *(float4*)(Wc + (2*g)*MCS + sl*4)   = A;
        *(float4*)(Wc + (2*g+1)*MCS + sl*4) = B;
        if(sl == 0){ s2[2*g] = fa; s2[2*g+1] = fb; }
    }
    __syncthreads();
    if(tid < 64){
        float v = s2[tid];
        for(int m = 32; m >= 1; m >>= 1) v = fmaxf(v, __shfl_xor(v, m, 64));
        if(tid == 0) smax_sh = sqrtf(v);
    }
    __syncthreads();
    if(tid < 64){
        float s = sqrtf(s2[tid]);
        float v = vp[0];
        float tau = 0.4f / (1.f + expf(-v));     // sigmoid(v)*COEF_GAMMA
        float thr = tau * smax_sh;
        coef3[tid] = (s > thr && s > 1e-20f) ? (s - thr) / (s*s*s) : 0.f;
    }
    __syncthreads();

    const float* Wc = P_WC;
    float* Tsh = P_TSH;
    // R1: T'[k][j] = coef3[k] * sum_r Wc[k][r] * Xsh[r][j]   (8 cols per thread)
    {
        int kk = tid >> 3;
        int j0 = (tid & 7) * 8;
        float acc[8];
        #pragma unroll
        for(int j = 0; j < 8; ++j) acc[j] = 0.f;
        for(int r = 0; r < 64; ++r){
            float wk = Wc[kk*MCS + r];
            const float* xr = Xsh + r*64 + j0;
            float4 x0 = *(const float4*)(xr);
            float4 x1 = *(const float4*)(xr + 4);
            acc[0]+=wk*x0.x; acc[1]+=wk*x0.y; acc[2]+=wk*x0.z; acc[3]+=wk*x0.w;
            acc[4]+=wk*x1.x; acc[5]+=wk*x1.y; acc[6]+=wk*x1.z; acc[7]+=wk*x1.w;
        }
        float c3 = coef3[kk];
        float* tr = Tsh + kk*64 + j0;
        float4 t0, t1;
        t0.x = c3*acc[0]; t0.y = c3*acc[1]; t0.z = c3*acc[2]; t0.w = c3*acc[3];
        t1.x = c3*acc[4]; t1.y = c3*acc[5]; t1.z = c3*acc[6]; t1.w = c3*acc[7];
        *(float4*)(tr)     = t0;
        *(float4*)(tr + 4) = t1;
    }
    __syncthreads();

    // R2: Ltmp[i][j] = sum_k Wc[k][i] * T'[k][j]; outputs   (8 cols per thread)
    {
        float neta = netap[0];
        int i  = tid >> 3;
        int j0 = (tid & 7) * 8;
        float acc[8];
        #pragma unroll
        for(int j = 0; j < 8; ++j) acc[j] = 0.f;
        for(int kk = 0; kk < 64; ++kk){
            float wik = Wc[kk*MCS + i];
            const float* tr = Tsh + kk*64 + j0;
            float4 t0 = *(const float4*)(tr);
            float4 t1 = *(const float4*)(tr + 4);
            acc[0]+=wik*t0.x; acc[1]+=wik*t0.y; acc[2]+=wik*t0.z; acc[3]+=wik*t0.w;
            acc[4]+=wik*t1.x; acc[5]+=wik*t1.y; acc[6]+=wik*t1.z; acc[7]+=wik*t1.w;
        }
        int n0 = i*64 + j0;
        #pragma unroll
        for(int c = 0; c < 2; ++c){
            float4 th = *(const float4*)(thP + n0 + 4*c);
            float4 lt, pt;
            lt.x = acc[4*c+0]; lt.y = acc[4*c+1]; lt.z = acc[4*c+2]; lt.w = acc[4*c+3];
            float4 xs = *(const float4*)(Xsh + n0 + 4*c);
            pt.x = th.x + neta * (xs.x - th.x - lt.x);
            pt.y = th.y + neta * (xs.y - th.y - lt.y);
            pt.z = th.z + neta * (xs.z - th.z - lt.z);
            pt.w = th.w + neta * (xs.w - th.w - lt.w);
            *(float4*)(out + n0 + 4*c)      = lt;
            *(float4*)(out + NN + n0 + 4*c) = pt;
        }
    }
}

extern "C" void kernel_launch(void* const* d_in, const int* in_sizes, int n_in,
                              void* d_out, int out_size, void* d_ws, size_t ws_size,
                              hipStream_t stream){
    const float* inp  = (const float*)d_in[0];
    const float* L    = (const float*)d_in[1];
    const int*   mask = (const int*)  d_in[2];
    const float* D    = (const float*)d_in[3];
    const float* thP  = (const float*)d_in[4];
    const float* vS   = (const float*)d_in[5];
    const float* neta = (const float*)d_in[6];
    const float* l1   = (const float*)d_in[7];
    const float* l2   = (const float*)d_in[8];
    const float* rho  = (const float*)d_in[9];
    const float* S    = (const float*)d_in[10];
    float* wf = (float*)d_ws;
    float* out = (float*)d_out;
    const bool use_bf16 = (ws_size >= WS_NEED_BF16);
    unsigned short* Dh = (unsigned short*)((char*)d_ws + DH_OFF_BYTES);

    float* Xb[2]  = { wf + OFF_X0, wf + OFF_X1 };
    float* Rb[2]  = { wf + OFF_R0, wf + OFF_R1 };
    float* Pb[2]  = { wf + OFF_P0, wf + OFF_P1 };
    float* Yb[2]  = { wf + OFF_Y0, wf + OFF_Y1 };
    float* pty[2] = { wf + OFF_PTY0, wf + OFF_PTY1 };

    if(use_bf16){
        // merged prep + iteration 0 (writes pty[0])
        k_fc<<<1024, 256, 0, stream>>>(D, Dh, inp, L, mask, thP, S,
                                       l1, l2, rho, wf, pty[0]);
        for(int j = 1; j < NITER; ++j){
            int ro = (j+1)&1, wr = j&1;
            k_step_h<<<1024, 256, 0, stream>>>(Dh, l1, l2, wf,
                Rb[ro], Pb[ro], Xb[ro], Yb[ro],
                Rb[wr], Pb[wr], Xb[wr],
                (j < NITER-1) ? Yb[wr] : (float*)nullptr,   // last y unused
                pty[(j-1)&1], pty[j&1]);
        }
    } else {
        k_prep<<<16, 256, 0, stream>>>(inp, L, mask, thP, S, l2, rho, wf);
        k_step_f<<<1024, 256, 0, stream>>>(D, l1, l2, wf,
            Rb[0], Pb[0], Xb[0], Yb[0], Rb[1], Pb[1], Xb[1], Yb[0],
            pty[0], pty[0], 0);
        for(int j = 1; j < NITER; ++j){
            int ro = (j+1)&1, wr = j&1;
            k_step_f<<<1024, 256, 0, stream>>>(D, l1, l2, wf,
                Rb[ro], Pb[ro], Xb[ro], Yb[ro],
                Rb[wr], Pb[wr], Xb[wr], Yb[wr],
                pty[(j-1)&1], pty[j&1], 1);
        }
    }
    // last write parity = (NITER-1)&1  (NITER=3 -> 0)
    const int lp = (NITER-1)&1;
    k_svt<<<1, 512, 0, stream>>>(thP, vS, neta, wf, Rb[lp], Pb[lp], Xb[lp],
                                 pty[lp], out);
}

// Round 11
// 273.148 us; speedup vs baseline: 1.0549x; 1.0012x over previous
//
#include <hip/hip_runtime.h>
#include <hip/hip_bf16.h>

#define NN 4096
#define NITER 3    // R10 ablation: passed, absmax unchanged (CG truncation < bf16 floor)
#define NSWEEP 5
#define MCS 68     // mailbox/Wc column stride (floats); [64] holds the column's squared norm

// workspace float layout (double-buffered CG vectors INCLUDING y)
#define OFF_STS  64
#define OFF_QRHO (OFF_STS + NN)
#define OFF_DINV (OFF_QRHO + NN)
#define OFF_Y0   (OFF_DINV + NN)
#define OFF_Y1   (OFF_Y0 + NN)
#define OFF_X0   (OFF_Y1 + NN)
#define OFF_X1   (OFF_X0 + NN)
#define OFF_R0   (OFF_X1 + NN)
#define OFF_R1   (OFF_R0 + NN)
#define OFF_P0   (OFF_R1 + NN)
#define OFF_P1   (OFF_P0 + NN)
// per-block pTy partials, double-buffered by iteration parity
#define OFF_PTY0 (OFF_P1 + NN)
#define OFF_PTY1 (OFF_PTY0 + 1024)
#define DH_OFF_BYTES 196608
#define WS_NEED_BF16 (DH_OFF_BYTES + (size_t)NN * NN * 2)

typedef unsigned int uint;
__device__ inline float lo2f(uint w){ return __uint_as_float(w << 16); }
__device__ inline float hi2f(uint w){ return __uint_as_float(w & 0xffff0000u); }
__device__ inline uint f2b(float f){
    uint u = __float_as_uint(f);
    return (u + 0x7FFFu + ((u >> 16) & 1u)) >> 16;   // RNE
}
// 16-lane sum via DPP only (VALU latency, no DS pipe). Valid when the 16 lanes
// of a group are an aligned 16-lane DPP row (group g = lanes 16g..16g+15).
__device__ inline float rsum16(float x){
    int a = __builtin_amdgcn_update_dpp(0, __float_as_int(x), 0xB1, 0xF, 0xF, true);
    float s = x + __int_as_float(a);
    int b = __builtin_amdgcn_update_dpp(0, __float_as_int(s), 0x4E, 0xF, 0xF, true);
    s = s + __int_as_float(b);
    int c = __builtin_amdgcn_update_dpp(0, __float_as_int(s), 0x141, 0xF, 0xF, true);  // row_half_mirror
    s = s + __int_as_float(c);
    int d = __builtin_amdgcn_update_dpp(0, __float_as_int(s), 0x140, 0xF, 0xF, true);  // row_mirror
    s = s + __int_as_float(d);
    return s;
}

// ---------------- prep (FALLBACK PATH ONLY): StS + b + approx diag + CG init ----------------
__global__ void k_prep(const float* __restrict__ inp, const float* __restrict__ L,
                       const int*  __restrict__ mask, const float* __restrict__ thP,
                       const float* __restrict__ S,
                       const float* __restrict__ l2p, const float* __restrict__ rhop,
                       float* __restrict__ wf){
    int t = blockIdx.x * 256 + threadIdx.x;   // 4096 threads
    int r = t >> 6, c = t & 63;
    float acc = 0.f, acc2 = 0.f;
    for(int h = 0; h < 64; ++h){
        float sr = S[h*64 + r];
        float sc = S[h*64 + c];
        acc  += sr * sc;
        acc2 += sc * sc;
    }
    wf[OFF_STS + t] = acc;
    float rho = rhop[0], l2 = l2p[0];
    float q = (mask[t] != 0) ? 1.f : 0.f;
    float bi = rho * (L[t] - thP[t]) + q * inp[t];
    float dinv = 1.f / (q + rho + l2 * acc2);   // preconditioner only
    wf[OFF_QRHO + t] = q + rho;
    wf[OFF_DINV + t] = dinv;
    wf[OFF_X0 + t]   = 0.f;
    wf[OFF_R0 + t]   = bi;
    wf[OFF_P0 + t]   = bi * dinv;
}

// ---------------- per-block redundant CG scalar update (no fences needed) ----------------
__device__ inline void cg_prologue(float* __restrict__ wf,
                                   const float* __restrict__ rold, const float* __restrict__ pold,
                                   const float* __restrict__ xold, const float* __restrict__ yold,
                                   float* __restrict__ rnew, float* __restrict__ pnew,
                                   float* __restrict__ xnew,
                                   const float* __restrict__ pty_read,
                                   float* __restrict__ psh,
                                   float* __restrict__ red){
    int tid = threadIdx.x;
    const float* dinv = wf + OFF_DINV;
    float4 r4[4], d4[4];
    float part = 0.f;
    #pragma unroll
    for(int k = 0; k < 4; ++k){
        r4[k] = ((const float4*)rold)[tid + k*256];
        d4[k] = ((const float4*)dinv)[tid + k*256];
        part += r4[k].x*r4[k].x*d4[k].x + r4[k].y*r4[k].y*d4[k].y
              + r4[k].z*r4[k].z*d4[k].z + r4[k].w*r4[k].w*d4[k].w;
    }
    float pp = pty_read[tid] + pty_read[tid+256] + pty_read[tid+512] + pty_read[tid+768];
    for(int m = 32; m >= 1; m >>= 1){
        part += __shfl_xor(part, m, 64);
        pp   += __shfl_xor(pp, m, 64);
    }
    int wave = tid >> 6, lane = tid & 63;
    if(lane == 0){ red[wave] = part; red[4+wave] = pp; }
    __syncthreads();
    float rzold = red[0] + red[1] + red[2] + red[3];
    float ptys  = red[4] + red[5] + red[6] + red[7];
    float alpha = rzold / ptys;
    float4 rn[4], zn[4];
    float part2 = 0.f;
    #pragma unroll
    for(int k = 0; k < 4; ++k){
        float4 y4 = ((const float4*)yold)[tid + k*256];
        rn[k].x = r4[k].x - alpha*y4.x;  rn[k].y = r4[k].y - alpha*y4.y;
        rn[k].z = r4[k].z - alpha*y4.z;  rn[k].w = r4[k].w - alpha*y4.w;
        zn[k].x = rn[k].x*d4[k].x;  zn[k].y = rn[k].y*d4[k].y;
        zn[k].z = rn[k].z*d4[k].z;  zn[k].w = rn[k].w*d4[k].w;
        part2 += rn[k].x*zn[k].x + rn[k].y*zn[k].y + rn[k].z*zn[k].z + rn[k].w*zn[k].w;
    }
    for(int m = 32; m >= 1; m >>= 1) part2 += __shfl_xor(part2, m, 64);
    __syncthreads();                      // all reads of red done
    if(lane == 0) red[wave] = part2;
    __syncthreads();
    float rznew = red[0] + red[1] + red[2] + red[3];
    float beta = rznew / rzold;
    bool b0 = (blockIdx.x == 0);
    #pragma unroll
    for(int k = 0; k < 4; ++k){
        float4 po = ((const float4*)pold)[tid + k*256];
        float4 pn;
        pn.x = zn[k].x + beta*po.x;  pn.y = zn[k].y + beta*po.y;
        pn.z = zn[k].z + beta*po.z;  pn.w = zn[k].w + beta*po.w;
        ((float4*)psh)[tid + k*256] = pn;
        if(b0){
            ((float4*)pnew)[tid + k*256] = pn;
            ((float4*)rnew)[tid + k*256] = rn[k];
            float4 xo = ((const float4*)xold)[tid + k*256];
            float4 xn;
            xn.x = xo.x + alpha*po.x;  xn.y = xo.y + alpha*po.y;
            xn.z = xo.z + alpha*po.z;  xn.w = xo.w + alpha*po.w;
            ((float4*)xnew)[tid + k*256] = xn;
        }
    }
    __syncthreads();
}

// ---------------- merged prep + CG step 0: fp32 D matvec + emit bf16 Dh ----------------
// R11: D-loop batched 4-deep. The old 1-load-in-flight loop was LATENCY-bound
// on ~900cy HBM reads (~0.8 TB/s); same loop on L2-hot Dh (k_step_h) hits
// ~5 TB/s. 4 independent loads issued before first use -> 4x MLP. Summation
// order is element-identical (jb*4+{0..3} == j), so dacc is bitwise unchanged.
__launch_bounds__(256)
__global__ void k_fc(const float* __restrict__ D, unsigned short* __restrict__ Dh,
                     const float* __restrict__ inp, const float* __restrict__ L,
                     const int*  __restrict__ mask, const float* __restrict__ thP,
                     const float* __restrict__ S,
                     const float* __restrict__ l1p, const float* __restrict__ l2p,
                     const float* __restrict__ rhop,
                     float* __restrict__ wf, float* __restrict__ pty_out){
    __shared__ float psh[NN];
    __shared__ float red[8];
    __shared__ float cparts[256];
    int tid = threadIdx.x;
    int wave = tid >> 6, lane = tid & 63;
    int row = blockIdx.x * 4 + wave;
    int u = row & 63, h = row >> 6;
    float l1 = l1p[0], l2 = l2p[0], rho = rhop[0];

    // S column-norm^2 partials (for dinv): wave w covers hh = 16w..16w+15
    {
        float cp = 0.f;
        for(int hh = wave*16; hh < wave*16 + 16; ++hh){
            float sv = S[hh*64 + lane];
            cp += sv * sv;
        }
        cparts[wave*64 + lane] = cp;
    }
    // StS row u (this wave's row), element 'lane'  (S is 16KB -> L1-hot)
    float stv = 0.f;
    for(int hh = 0; hh < 64; ++hh)
        stv += S[hh*64 + u] * S[hh*64 + lane];
    if(row < 64) wf[OFF_STS + row*64 + lane] = stv;   // canonical StS (blocks 0..15)
    __syncthreads();

    // build p0 into psh (redundant per block); canonical inits from blocks 0..15
    int c = tid & 63;
    float cs4 = cparts[c] + cparts[64+c] + cparts[128+c] + cparts[192+c];
    bool canon = (blockIdx.x < 16);
    for(int k = 0; k < 16; ++k){
        int t = tid + k*256;                    // t&63 == tid&63
        float q = (mask[t] != 0) ? 1.f : 0.f;
        float bi = rho * (L[t] - thP[t]) + q * inp[t];
        float dinv = 1.f / (q + rho + l2 * cs4);
        psh[t] = bi * dinv;
        if(canon && k == (int)blockIdx.x){
            wf[OFF_QRHO + t] = q + rho;
            wf[OFF_DINV + t] = dinv;
            wf[OFF_X0 + t]   = 0.f;
            wf[OFF_R0 + t]   = bi;
            wf[OFF_P0 + t]   = bi * dinv;
        }
    }
    __syncthreads();

    // fp32 matvec + emit bf16 Dh, 4 loads in flight
    const float* Drow = D + (size_t)row * NN;
    unsigned short* Dhrow = Dh + (size_t)row * NN;
    float dacc = 0.f;
    for(int jb = 0; jb < 4; ++jb){
        int c0 = jb*1024 + lane*4;
        float4 d0 = *(const float4*)(Drow + c0);
        float4 d1 = *(const float4*)(Drow + c0 + 256);
        float4 d2 = *(const float4*)(Drow + c0 + 512);
        float4 d3 = *(const float4*)(Drow + c0 + 768);
        float4 p0 = *(const float4*)(psh + c0);
        float4 p1 = *(const float4*)(psh + c0 + 256);
        float4 p2 = *(const float4*)(psh + c0 + 512);
        float4 p3 = *(const float4*)(psh + c0 + 768);
        dacc += d0.x*p0.x + d0.y*p0.y + d0.z*p0.z + d0.w*p0.w;
        dacc += d1.x*p1.x + d1.y*p1.y + d1.z*p1.z + d1.w*p1.w;
        dacc += d2.x*p2.x + d2.y*p2.y + d2.z*p2.z + d2.w*p2.w;
        dacc += d3.x*p3.x + d3.y*p3.y + d3.z*p3.z + d3.w*p3.w;
        uint2 o0, o1, o2, o3;
        o0.x = f2b(d0.x) | (f2b(d0.y) << 16);  o0.y = f2b(d0.z) | (f2b(d0.w) << 16);
        o1.x = f2b(d1.x) | (f2b(d1.y) << 16);  o1.y = f2b(d1.z) | (f2b(d1.w) << 16);
        o2.x = f2b(d2.x) | (f2b(d2.y) << 16);  o2.y = f2b(d2.z) | (f2b(d2.w) << 16);
        o3.x = f2b(d3.x) | (f2b(d3.y) << 16);  o3.y = f2b(d3.z) | (f2b(d3.w) << 16);
        *(uint2*)(Dhrow + c0)       = o0;
        *(uint2*)(Dhrow + c0 + 256) = o1;
        *(uint2*)(Dhrow + c0 + 512) = o2;
        *(uint2*)(Dhrow + c0 + 768) = o3;
    }
    float sacc = stv * psh[h*64 + lane];
    float val = l1 * dacc + l2 * sacc;
    for(int m = 32; m >= 1; m >>= 1) val += __shfl_xor(val, m, 64);
    if(lane == 0){
        float qr = ((mask[row] != 0) ? 1.f : 0.f) + rho;   // local (canonical QRHO may race in-kernel)
        float yi = val + qr * psh[row];
        (wf + OFF_Y0)[row] = yi;
        red[wave] = yi * psh[row];
    }
    __syncthreads();
    if(tid == 0) pty_out[blockIdx.x] = red[0] + red[1] + red[2] + red[3];
}

// ---------------- CG step j>=1: prologue + y = A p (bf16 D) + pTy partial ----------------
__launch_bounds__(256)
__global__ void k_step_h(const unsigned short* __restrict__ Dh,
                         const float* __restrict__ l1p, const float* __restrict__ l2p,
                         float* __restrict__ wf,
                         const float* __restrict__ rold, const float* __restrict__ pold,
                         const float* __restrict__ xold, const float* __restrict__ yold,
                         float* __restrict__ rnew, float* __restrict__ pnew,
                         float* __restrict__ xnew, float* __restrict__ ynew,
                         const float* __restrict__ pty_read, float* __restrict__ pty_write){
    __shared__ float psh[NN];
    __shared__ float red[8];
    int tid = threadIdx.x;
    cg_prologue(wf, rold, pold, xold, yold, rnew, pnew, xnew, pty_read, psh, red);

    float l1 = l1p[0], l2 = l2p[0];
    int wave = tid >> 6, lane = tid & 63;
    int row = blockIdx.x * 4 + wave;
    int h = row >> 6, u = row & 63;
    const float* qrho = wf + OFF_QRHO;
    const float* StS  = wf + OFF_STS;

    // bf16 matvec, 2 loads in flight (same element order as before: j = 2jb, 2jb+1)
    const unsigned short* Drow = Dh + (size_t)row * NN;
    float dacc = 0.f;
    for(int jb = 0; jb < 4; ++jb){
        int c0 = jb*1024 + lane*8;
        uint4 dv0 = *(const uint4*)(Drow + c0);
        uint4 dv1 = *(const uint4*)(Drow + c0 + 512);
        float4 pa0 = *(const float4*)(psh + c0);
        float4 pb0 = *(const float4*)(psh + c0 + 4);
        float4 pa1 = *(const float4*)(psh + c0 + 512);
        float4 pb1 = *(const float4*)(psh + c0 + 516);
        dacc += lo2f(dv0.x)*pa0.x + hi2f(dv0.x)*pa0.y
              + lo2f(dv0.y)*pa0.z + hi2f(dv0.y)*pa0.w
              + lo2f(dv0.z)*pb0.x + hi2f(dv0.z)*pb0.y
              + lo2f(dv0.w)*pb0.z + hi2f(dv0.w)*pb0.w;
        dacc += lo2f(dv1.x)*pa1.x + hi2f(dv1.x)*pa1.y
              + lo2f(dv1.y)*pa1.z + hi2f(dv1.y)*pa1.w
              + lo2f(dv1.z)*pb1.x + hi2f(dv1.z)*pb1.y
              + lo2f(dv1.w)*pb1.z + hi2f(dv1.w)*pb1.w;
    }
    float sacc = StS[u*64 + lane] * psh[h*64 + lane];
    float val = l1 * dacc + l2 * sacc;
    for(int m = 32; m >= 1; m >>= 1) val += __shfl_xor(val, m, 64);
    if(lane == 0){
        float yi = val + qrho[row] * psh[row];
        if(ynew) ynew[row] = yi;          // last iteration's y is never consumed
        red[wave] = yi * psh[row];
    }
    __syncthreads();
    if(tid == 0) pty_write[blockIdx.x] = red[0] + red[1] + red[2] + red[3];
}

// ---------------- CG step fp32 fallback (do_pro selects prologue) ----------------
__launch_bounds__(256)
__global__ void k_step_f(const float* __restrict__ D,
                         const float* __restrict__ l1p, const float* __restrict__ l2p,
                         float* __restrict__ wf,
                         const float* __restrict__ rold, const float* __restrict__ pold,
                         const float* __restrict__ xold, const float* __restrict__ yold,
                         float* __restrict__ rnew, float* __restrict__ pnew,
                         float* __restrict__ xnew, float* __restrict__ ynew,
                         const float* __restrict__ pty_read, float* __restrict__ pty_write,
                         int do_pro){
    __shared__ float psh[NN];
    __shared__ float red[8];
    int tid = threadIdx.x;
    if(do_pro){
        cg_prologue(wf, rold, pold, xold, yold, rnew, pnew, xnew, pty_read, psh, red);
    } else {
        for(int k = 0; k < 4; ++k)
            ((float4*)psh)[tid + k*256] = ((const float4*)pold)[tid + k*256];
        __syncthreads();
    }
    float l1 = l1p[0], l2 = l2p[0];
    int wave = tid >> 6, lane = tid & 63;
    int row = blockIdx.x * 4 + wave;
    int h = row >> 6, u = row & 63;
    const float* qrho = wf + OFF_QRHO;
    const float* StS  = wf + OFF_STS;
    const float* Drow = D + (size_t)row * NN;
    float dacc = 0.f;
    for(int j = 0; j < 16; ++j){
        int c0 = j*256 + lane*4;
        float4 dv = *(const float4*)(Drow + c0);
        float4 pa = *(const float4*)(psh + c0);
        dacc += dv.x*pa.x + dv.y*pa.y + dv.z*pa.z + dv.w*pa.w;
    }
    float sacc = StS[u*64 + lane] * psh[h*64 + lane];
    float val = l1 * dacc + l2 * sacc;
    for(int m = 32; m >= 1; m >>= 1) val += __shfl_xor(val, m, 64);
    if(lane == 0){
        float yi = val + qrho[row] * psh[row];
        ynew[row] = yi;
        red[wave] = yi * psh[row];
    }
    __syncthreads();
    if(tid == 0) pty_write[blockIdx.x] = red[0] + red[1] + red[2] + red[3];
}

// ---------------- SVT: register-resident Brent-Luk Jacobi + final CG update fused ----------------
// 512 threads = 32 groups x 16 sublanes; each sublane owns 4 rows (one float4).
// R8 A/B: 256-thr variant loses (bank conflicts x3). Keep sl*4 / 8 waves.
#define P_MA(par) (POOL + (par)*2176)
#define P_MB(par) (POOL + 4352 + (par)*2176)
#define P_XSH     (POOL + 8704)
#define P_TSH     (POOL)
#define P_WC      (POOL + 4352)
#define DOT4(u,v) ((u).x*(v).x + (u).y*(v).y + (u).z*(v).z + (u).w*(v).w)

__launch_bounds__(512)
__global__ void k_svt(const float* __restrict__ thP, const float* __restrict__ vp,
                      const float* __restrict__ netap,
                      float* __restrict__ wf,
                      const float* __restrict__ rlast, const float* __restrict__ plast,
                      const float* __restrict__ xlast,
                      const float* __restrict__ ptyp,
                      float* __restrict__ out){
    __shared__ float POOL[12800];
    __shared__ float s2[64], coef3[64];
    __shared__ float smax_sh;
    __shared__ float redv[16];
    int tid = threadIdx.x;
    float* Xsh = P_XSH;

    // fused final CG update: alpha_last = rz_last / pTy_last ; X = x + alpha*p + thP
    {
        const float* dinv = wf + OFF_DINV;
        float part = 0.f;
        #pragma unroll
        for(int k = 0; k < 2; ++k){
            float4 r4 = ((const float4*)rlast)[tid + k*512];
            float4 d4 = ((const float4*)dinv)[tid + k*512];
            part += r4.x*r4.x*d4.x + r4.y*r4.y*d4.y + r4.z*r4.z*d4.z + r4.w*r4.w*d4.w;
        }
        float pp = ptyp[tid] + ptyp[tid + 512];
        for(int m = 32; m >= 1; m >>= 1){
            part += __shfl_xor(part, m, 64);
            pp   += __shfl_xor(pp, m, 64);
        }
        if((tid & 63) == 0){ redv[tid >> 6] = part; redv[8 + (tid >> 6)] = pp; }
        __syncthreads();
        float rz = redv[0] + redv[1] + redv[2] + redv[3]
                 + redv[4] + redv[5] + redv[6] + redv[7];
        float ptys = redv[8] + redv[9] + redv[10] + redv[11]
                   + redv[12] + redv[13] + redv[14] + redv[15];
        float a = rz / ptys;
        #pragma unroll
        for(int k = 0; k < 2; ++k){
            float4 x4 = ((const float4*)xlast)[tid + k*512];
            float4 p4 = ((const float4*)plast)[tid + k*512];
            float4 t4 = ((const float4*)thP)[tid + k*512];
            float4 v;
            v.x = x4.x + a*p4.x + t4.x;  v.y = x4.y + a*p4.y + t4.y;
            v.z = x4.z + a*p4.z + t4.z;  v.w = x4.w + a*p4.w + t4.w;
            ((float4*)Xsh)[tid + k*512] = v;
        }
    }
    __syncthreads();

    int g  = tid >> 4;      // group 0..31 (one aligned 16-lane DPP row)
    int sl = tid & 15;      // sub-lane: rows sl*4 .. sl*4+3
    float4 A, B;
    {
        int ca = 2*g, cb = 2*g + 1, r0 = sl*4;
        A.x = Xsh[(r0+0)*64+ca]; A.y = Xsh[(r0+1)*64+ca];
        A.z = Xsh[(r0+2)*64+ca]; A.w = Xsh[(r0+3)*64+ca];
        B.x = Xsh[(r0+0)*64+cb]; B.y = Xsh[(r0+1)*64+cb];
        B.z = Xsh[(r0+2)*64+cb]; B.w = Xsh[(r0+3)*64+cb];
    }
    float aa = rsum16(DOT4(A,A));
    float bb = rsum16(DOT4(B,B));

    const int total = NSWEEP * 63;
    for(int gr = 0; gr < total; ++gr){
        float cc = rsum16(DOT4(A,B));
        // branch-free angle, 3 transcendentals:
        // d=bb-aa; s=sqrt(d^2+4c^2); t = sgn(d)*2c/(|d|+s)
        float dd = bb - aa;
        float c2 = cc + cc;
        float s  = __builtin_amdgcn_sqrtf(__builtin_fmaf(dd, dd, c2*c2));
        float t0 = c2 * __builtin_amdgcn_rcpf(fabsf(dd) + s + 1e-30f);
        float t  = (dd < 0.f) ? -t0 : t0;
        float cs = __builtin_amdgcn_rsqf(__builtin_fmaf(t, t, 1.f));
        float sn = t * cs;
        float naN = aa - t*cc;      // rotated-A squared norm (Golub update)
        float nbN = bb + t*cc;      // rotated-B squared norm
        if(gr != total - 1){
            int par = gr & 1;
            float* MAp = P_MA(par);
            float* MBp = P_MB(par);
            // rotate & ship outgoing B first (overlap write latency with A rotation)
            float4 nb;
            nb.x = sn*A.x + cs*B.x; nb.y = sn*A.y + cs*B.y;
            nb.z = sn*A.z + cs*B.z; nb.w = sn*A.w + cs*B.w;
            float* cbB = (g == 0) ? (MAp + 1*MCS) : (MBp + (g-1)*MCS);
            *(float4*)(cbB + sl*4) = nb;
            if(sl == 0) cbB[64] = nbN;
            float4 na;
            na.x = cs*A.x - sn*B.x; na.y = cs*A.y - sn*B.y;
            na.z = cs*A.z - sn*B.z; na.w = cs*A.w - sn*B.w;
            if(g >= 1 && g <= 30){
                float* cbA = MAp + (g+1)*MCS;
                *(float4*)(cbA + sl*4) = na;
                if(sl == 0) cbA[64] = naN;
            }
            __syncthreads();
            float4 nA = na;  float nAa = naN;   // g==0 keeps rotated A
            float4 nB = na;  float nBb = naN;   // g==31: new B = rotated A
            if(g >= 1){
                const float* ra = MAp + g*MCS;
                nA = *(const float4*)(ra + sl*4);
                nAa = ra[64];
            }
            if(g <= 30){
                const float* rb = MBp + g*MCS;
                nB = *(const float4*)(rb + sl*4);
                nBb = rb[64];
            }
            A = nA; B = nB; aa = nAa; bb = nBb;
        } else {
            float4 na;
            na.x = cs*A.x - sn*B.x; na.y = cs*A.y - sn*B.y;
            na.z = cs*A.z - sn*B.z; na.w = cs*A.w - sn*B.w;
            float4 nbf;
            nbf.x = sn*A.x + cs*B.x; nbf.y = sn*A.y + cs*B.y;
            nbf.z = sn*A.z + cs*B.z; nbf.w = sn*A.w + cs*B.w;
            A = na; B = nbf;
        }
    }
    // final column norms (exact, drift-free) + store W to LDS
    {
        float fa = rsum16(DOT4(A,A));
        float fb = rsum16(DOT4(B,B));
        __syncthreads();   // mailbox reads done before Wc (aliases MB) written
        float* Wc = P_WC;
        *(float4*)(Wc + (2*g)*MCS + sl*4)   = A;
        *(float4*)(Wc + (2*g+1)*MCS + sl*4) = B;
        if(sl == 0){ s2[2*g] = fa; s2[2*g+1] = fb; }
    }
    __syncthreads();
    if(tid < 64){
        float v = s2[tid];
        for(int m = 32; m >= 1; m >>= 1) v = fmaxf(v, __shfl_xor(v, m, 64));
        if(tid == 0) smax_sh = sqrtf(v);
    }
    __syncthreads();
    if(tid < 64){
        float s = sqrtf(s2[tid]);
        float v = vp[0];
        float tau = 0.4f / (1.f + expf(-v));     // sigmoid(v)*COEF_GAMMA
        float thr = tau * smax_sh;
        coef3[tid] = (s > thr && s > 1e-20f) ? (s - thr) / (s*s*s) : 0.f;
    }
    __syncthreads();

    const float* Wc = P_WC;
    float* Tsh = P_TSH;
    // R1: T'[k][j] = coef3[k] * sum_r Wc[k][r] * Xsh[r][j]   (8 cols per thread)
    {
        int kk = tid >> 3;
        int j0 = (tid & 7) * 8;
        float acc[8];
        #pragma unroll
        for(int j = 0; j < 8; ++j) acc[j] = 0.f;
        for(int r = 0; r < 64; ++r){
            float wk = Wc[kk*MCS + r];
            const float* xr = Xsh + r*64 + j0;
            float4 x0 = *(const float4*)(xr);
            float4 x1 = *(const float4*)(xr + 4);
            acc[0]+=wk*x0.x; acc[1]+=wk*x0.y; acc[2]+=wk*x0.z; acc[3]+=wk*x0.w;
            acc[4]+=wk*x1.x; acc[5]+=wk*x1.y; acc[6]+=wk*x1.z; acc[7]+=wk*x1.w;
        }
        float c3 = coef3[kk];
        float* tr = Tsh + kk*64 + j0;
        float4 t0, t1;
        t0.x = c3*acc[0]; t0.y = c3*acc[1]; t0.z = c3*acc[2]; t0.w = c3*acc[3];
        t1.x = c3*acc[4]; t1.y = c3*acc[5]; t1.z = c3*acc[6]; t1.w = c3*acc[7];
        *(float4*)(tr)     = t0;
        *(float4*)(tr + 4) = t1;
    }
    __syncthreads();

    // R2: Ltmp[i][j] = sum_k Wc[k][i] * T'[k][j]; outputs   (8 cols per thread)
    {
        float neta = netap[0];
        int i  = tid >> 3;
        int j0 = (tid & 7) * 8;
        float acc[8];
        #pragma unroll
        for(int j = 0; j < 8; ++j) acc[j] = 0.f;
        for(int kk = 0; kk < 64; ++kk){
            float wik = Wc[kk*MCS + i];
            const float* tr = Tsh + kk*64 + j0;
            float4 t0 = *(const float4*)(tr);
            float4 t1 = *(const float4*)(tr + 4);
            acc[0]+=wik*t0.x; acc[1]+=wik*t0.y; acc[2]+=wik*t0.z; acc[3]+=wik*t0.w;
            acc[4]+=wik*t1.x; acc[5]+=wik*t1.y; acc[6]+=wik*t1.z; acc[7]+=wik*t1.w;
        }
        int n0 = i*64 + j0;
        #pragma unroll
        for(int c = 0; c < 2; ++c){
            float4 th = *(const float4*)(thP + n0 + 4*c);
            float4 lt, pt;
            lt.x = acc[4*c+0]; lt.y = acc[4*c+1]; lt.z = acc[4*c+2]; lt.w = acc[4*c+3];
            float4 xs = *(const float4*)(Xsh + n0 + 4*c);
            pt.x = th.x + neta * (xs.x - th.x - lt.x);
            pt.y = th.y + neta * (xs.y - th.y - lt.y);
            pt.z = th.z + neta * (xs.z - th.z - lt.z);
            pt.w = th.w + neta * (xs.w - th.w - lt.w);
            *(float4*)(out + n0 + 4*c)      = lt;
            *(float4*)(out + NN + n0 + 4*c) = pt;
        }
    }
}

extern "C" void kernel_launch(void* const* d_in, const int* in_sizes, int n_in,
                              void* d_out, int out_size, void* d_ws, size_t ws_size,
                              hipStream_t stream){
    const float* inp  = (const float*)d_in[0];
    const float* L    = (const float*)d_in[1];
    const int*   mask = (const int*)  d_in[2];
    const float* D    = (const float*)d_in[3];
    const float* thP  = (const float*)d_in[4];
    const float* vS   = (const float*)d_in[5];
    const float* neta = (const float*)d_in[6];
    const float* l1   = (const float*)d_in[7];
    const float* l2   = (const float*)d_in[8];
    const float* rho  = (const float*)d_in[9];
    const float* S    = (const float*)d_in[10];
    float* wf = (float*)d_ws;
    float* out = (float*)d_out;
    const bool use_bf16 = (ws_size >= WS_NEED_BF16);
    unsigned short* Dh = (unsigned short*)((char*)d_ws + DH_OFF_BYTES);

    float* Xb[2]  = { wf + OFF_X0, wf + OFF_X1 };
    float* Rb[2]  = { wf + OFF_R0, wf + OFF_R1 };
    float* Pb[2]  = { wf + OFF_P0, wf + OFF_P1 };
    float* Yb[2]  = { wf + OFF_Y0, wf + OFF_Y1 };
    float* pty[2] = { wf + OFF_PTY0, wf + OFF_PTY1 };

    if(use_bf16){
        // merged prep + iteration 0 (writes pty[0])
        k_fc<<<1024, 256, 0, stream>>>(D, Dh, inp, L, mask, thP, S,
                                       l1, l2, rho, wf, pty[0]);
        for(int j = 1; j < NITER; ++j){
            int ro = (j+1)&1, wr = j&1;
            k_step_h<<<1024, 256, 0, stream>>>(Dh, l1, l2, wf,
                Rb[ro], Pb[ro], Xb[ro], Yb[ro],
                Rb[wr], Pb[wr], Xb[wr],
                (j < NITER-1) ? Yb[wr] : (float*)nullptr,   // last y unused
                pty[(j-1)&1], pty[j&1]);
        }
    } else {
        k_prep<<<16, 256, 0, stream>>>(inp, L, mask, thP, S, l2, rho, wf);
        k_step_f<<<1024, 256, 0, stream>>>(D, l1, l2, wf,
            Rb[0], Pb[0], Xb[0], Yb[0], Rb[1], Pb[1], Xb[1], Yb[0],
            pty[0], pty[0], 0);
        for(int j = 1; j < NITER; ++j){
            int ro = (j+1)&1, wr = j&1;
            k_step_f<<<1024, 256, 0, stream>>>(D, l1, l2, wf,
                Rb[ro], Pb[ro], Xb[ro], Yb[ro],
                Rb[wr], Pb[wr], Xb[wr], Yb[wr],
                pty[(j-1)&1], pty[j&1], 1);
        }
    }
    // last write parity = (NITER-1)&1  (NITER=3 -> 0)
    const int lp = (NITER-1)&1;
    k_svt<<<1, 512, 0, stream>>>(thP, vS, neta, wf, Rb[lp], Pb[lp], Xb[lp],
                                 pty[lp], out);
}

// Round 12
// 265.268 us; speedup vs baseline: 1.0862x; 1.0297x over previous
//
#include <hip/hip_runtime.h>
#include <hip/hip_bf16.h>

#define NN 4096
#define NITER 3    // R10 ablation: passed, absmax unchanged (CG truncation < bf16 floor)
#define NSWEEP 5
#define MCS 68     // mailbox/Wc column stride (floats); [64] holds the column's squared norm

// workspace float layout (double-buffered CG vectors INCLUDING y)
#define OFF_STS  64
#define OFF_QRHO (OFF_STS + NN)
#define OFF_DINV (OFF_QRHO + NN)
#define OFF_Y0   (OFF_DINV + NN)
#define OFF_Y1   (OFF_Y0 + NN)
#define OFF_X0   (OFF_Y1 + NN)
#define OFF_X1   (OFF_X0 + NN)
#define OFF_R0   (OFF_X1 + NN)
#define OFF_R1   (OFF_R0 + NN)
#define OFF_P0   (OFF_R1 + NN)
#define OFF_P1   (OFF_P0 + NN)
// per-block pTy partials, double-buffered by iteration parity
#define OFF_PTY0 (OFF_P1 + NN)
#define OFF_PTY1 (OFF_PTY0 + 1024)
#define DH_OFF_BYTES 196608
#define WS_NEED_BF16 (DH_OFF_BYTES + (size_t)NN * NN * 2)

typedef unsigned int uint;
__device__ inline float lo2f(uint w){ return __uint_as_float(w << 16); }
__device__ inline float hi2f(uint w){ return __uint_as_float(w & 0xffff0000u); }
__device__ inline uint f2b(float f){
    uint u = __float_as_uint(f);
    return (u + 0x7FFFu + ((u >> 16) & 1u)) >> 16;   // RNE
}
// 16-lane sum via DPP only (VALU latency, no DS pipe). Valid when the 16 lanes
// of a group are an aligned 16-lane DPP row (group g = lanes 16g..16g+15).
__device__ inline float rsum16(float x){
    int a = __builtin_amdgcn_update_dpp(0, __float_as_int(x), 0xB1, 0xF, 0xF, true);
    float s = x + __int_as_float(a);
    int b = __builtin_amdgcn_update_dpp(0, __float_as_int(s), 0x4E, 0xF, 0xF, true);
    s = s + __int_as_float(b);
    int c = __builtin_amdgcn_update_dpp(0, __float_as_int(s), 0x141, 0xF, 0xF, true);  // row_half_mirror
    s = s + __int_as_float(c);
    int d = __builtin_amdgcn_update_dpp(0, __float_as_int(s), 0x140, 0xF, 0xF, true);  // row_mirror
    s = s + __int_as_float(d);
    return s;
}

// ---------------- prep body (shared): StS + b + approx diag + CG init ----------------
__device__ inline void prep_body(int t,
                                 const float* __restrict__ inp, const float* __restrict__ L,
                                 const int*  __restrict__ mask, const float* __restrict__ thP,
                                 const float* __restrict__ S,
                                 float l2, float rho, float* __restrict__ wf){
    int r = t >> 6, c = t & 63;
    float acc = 0.f, acc2 = 0.f;
    for(int h = 0; h < 64; ++h){
        float sr = S[h*64 + r];
        float sc = S[h*64 + c];
        acc  += sr * sc;
        acc2 += sc * sc;
    }
    wf[OFF_STS + t] = acc;
    float q = (mask[t] != 0) ? 1.f : 0.f;
    float bi = rho * (L[t] - thP[t]) + q * inp[t];
    float dinv = 1.f / (q + rho + l2 * acc2);   // preconditioner only
    wf[OFF_QRHO + t] = q + rho;
    wf[OFF_DINV + t] = dinv;
    wf[OFF_X0 + t]   = 0.f;
    wf[OFF_R0 + t]   = bi;
    wf[OFF_P0 + t]   = bi * dinv;
}

// ---------------- prep (FALLBACK PATH ONLY) ----------------
__global__ void k_prep(const float* __restrict__ inp, const float* __restrict__ L,
                       const int*  __restrict__ mask, const float* __restrict__ thP,
                       const float* __restrict__ S,
                       const float* __restrict__ l2p, const float* __restrict__ rhop,
                       float* __restrict__ wf){
    int t = blockIdx.x * 256 + threadIdx.x;   // 4096 threads
    prep_body(t, inp, L, mask, thP, S, l2p[0], rhop[0], wf);
}

// ---------------- R12: pure-streaming convert D -> bf16 Dh, + prep on 16 blocks ----------------
// Decisive experiment: the old k_fc (prep + fp32 matvec + fused convert behind an
// LDS dependency) resisted 4x MLP batching (R11 null). This kernel is dependency-
// free coalesced streaming (96 MB); if IT is also slow, the cost was never k_fc's
// code and the residual is fixed overhead. Iteration 0 moves to the bf16 path
// (k_step_h0) -> CG now solves the CONSISTENT bf16-perturbed system.
__launch_bounds__(256)
__global__ void k_conv(const float* __restrict__ D, unsigned short* __restrict__ Dh,
                       const float* __restrict__ inp, const float* __restrict__ L,
                       const int*  __restrict__ mask, const float* __restrict__ thP,
                       const float* __restrict__ S,
                       const float* __restrict__ l2p, const float* __restrict__ rhop,
                       float* __restrict__ wf){
    int tid = threadIdx.x;
    if(blockIdx.x < 16){
        prep_body(blockIdx.x * 256 + tid, inp, L, mask, thP, S, l2p[0], rhop[0], wf);
        return;
    }
    // blocks 16..2063: convert 2048 float4 each (coalesced read + write)
    size_t base = (size_t)(blockIdx.x - 16) * 2048 + tid;
    const float4* D4 = (const float4*)D;
    #pragma unroll
    for(int k = 0; k < 8; ++k){
        size_t f = base + (size_t)k * 256;
        float4 dv = D4[f];
        uint2 o;
        o.x = f2b(dv.x) | (f2b(dv.y) << 16);
        o.y = f2b(dv.z) | (f2b(dv.w) << 16);
        *(uint2*)(Dh + f*4) = o;
    }
}

// ---------------- per-block redundant CG scalar update (no fences needed) ----------------
__device__ inline void cg_prologue(float* __restrict__ wf,
                                   const float* __restrict__ rold, const float* __restrict__ pold,
                                   const float* __restrict__ xold, const float* __restrict__ yold,
                                   float* __restrict__ rnew, float* __restrict__ pnew,
                                   float* __restrict__ xnew,
                                   const float* __restrict__ pty_read,
                                   float* __restrict__ psh,
                                   float* __restrict__ red){
    int tid = threadIdx.x;
    const float* dinv = wf + OFF_DINV;
    float4 r4[4], d4[4];
    float part = 0.f;
    #pragma unroll
    for(int k = 0; k < 4; ++k){
        r4[k] = ((const float4*)rold)[tid + k*256];
        d4[k] = ((const float4*)dinv)[tid + k*256];
        part += r4[k].x*r4[k].x*d4[k].x + r4[k].y*r4[k].y*d4[k].y
              + r4[k].z*r4[k].z*d4[k].z + r4[k].w*r4[k].w*d4[k].w;
    }
    float pp = pty_read[tid] + pty_read[tid+256] + pty_read[tid+512] + pty_read[tid+768];
    for(int m = 32; m >= 1; m >>= 1){
        part += __shfl_xor(part, m, 64);
        pp   += __shfl_xor(pp, m, 64);
    }
    int wave = tid >> 6, lane = tid & 63;
    if(lane == 0){ red[wave] = part; red[4+wave] = pp; }
    __syncthreads();
    float rzold = red[0] + red[1] + red[2] + red[3];
    float ptys  = red[4] + red[5] + red[6] + red[7];
    float alpha = rzold / ptys;
    float4 rn[4], zn[4];
    float part2 = 0.f;
    #pragma unroll
    for(int k = 0; k < 4; ++k){
        float4 y4 = ((const float4*)yold)[tid + k*256];
        rn[k].x = r4[k].x - alpha*y4.x;  rn[k].y = r4[k].y - alpha*y4.y;
        rn[k].z = r4[k].z - alpha*y4.z;  rn[k].w = r4[k].w - alpha*y4.w;
        zn[k].x = rn[k].x*d4[k].x;  zn[k].y = rn[k].y*d4[k].y;
        zn[k].z = rn[k].z*d4[k].z;  zn[k].w = rn[k].w*d4[k].w;
        part2 += rn[k].x*zn[k].x + rn[k].y*zn[k].y + rn[k].z*zn[k].z + rn[k].w*zn[k].w;
    }
    for(int m = 32; m >= 1; m >>= 1) part2 += __shfl_xor(part2, m, 64);
    __syncthreads();                      // all reads of red done
    if(lane == 0) red[wave] = part2;
    __syncthreads();
    float rznew = red[0] + red[1] + red[2] + red[3];
    float beta = rznew / rzold;
    bool b0 = (blockIdx.x == 0);
    #pragma unroll
    for(int k = 0; k < 4; ++k){
        float4 po = ((const float4*)pold)[tid + k*256];
        float4 pn;
        pn.x = zn[k].x + beta*po.x;  pn.y = zn[k].y + beta*po.y;
        pn.z = zn[k].z + beta*po.z;  pn.w = zn[k].w + beta*po.w;
        ((float4*)psh)[tid + k*256] = pn;
        if(b0){
            ((float4*)pnew)[tid + k*256] = pn;
            ((float4*)rnew)[tid + k*256] = rn[k];
            float4 xo = ((const float4*)xold)[tid + k*256];
            float4 xn;
            xn.x = xo.x + alpha*po.x;  xn.y = xo.y + alpha*po.y;
            xn.z = xo.z + alpha*po.z;  xn.w = xo.w + alpha*po.w;
            ((float4*)xnew)[tid + k*256] = xn;
        }
    }
    __syncthreads();
}

// ---------------- shared bf16 matvec tail (batched 2-deep; element order == j-loop) ----------------
__device__ inline void bf16_matvec_tail(const unsigned short* __restrict__ Dh,
                                        float l1, float l2,
                                        const float* __restrict__ wf,
                                        float* __restrict__ psh, float* __restrict__ red,
                                        float* __restrict__ ynew,
                                        float* __restrict__ pty_write){
    int tid = threadIdx.x;
    int wave = tid >> 6, lane = tid & 63;
    int row = blockIdx.x * 4 + wave;
    int h = row >> 6, u = row & 63;
    const float* qrho = wf + OFF_QRHO;
    const float* StS  = wf + OFF_STS;
    const unsigned short* Drow = Dh + (size_t)row * NN;
    float dacc = 0.f;
    for(int jb = 0; jb < 4; ++jb){
        int c0 = jb*1024 + lane*8;
        uint4 dv0 = *(const uint4*)(Drow + c0);
        uint4 dv1 = *(const uint4*)(Drow + c0 + 512);
        float4 pa0 = *(const float4*)(psh + c0);
        float4 pb0 = *(const float4*)(psh + c0 + 4);
        float4 pa1 = *(const float4*)(psh + c0 + 512);
        float4 pb1 = *(const float4*)(psh + c0 + 516);
        dacc += lo2f(dv0.x)*pa0.x + hi2f(dv0.x)*pa0.y
              + lo2f(dv0.y)*pa0.z + hi2f(dv0.y)*pa0.w
              + lo2f(dv0.z)*pb0.x + hi2f(dv0.z)*pb0.y
              + lo2f(dv0.w)*pb0.z + hi2f(dv0.w)*pb0.w;
        dacc += lo2f(dv1.x)*pa1.x + hi2f(dv1.x)*pa1.y
              + lo2f(dv1.y)*pa1.z + hi2f(dv1.y)*pa1.w
              + lo2f(dv1.z)*pb1.x + hi2f(dv1.z)*pb1.y
              + lo2f(dv1.w)*pb1.z + hi2f(dv1.w)*pb1.w;
    }
    float sacc = StS[u*64 + lane] * psh[h*64 + lane];
    float val = l1 * dacc + l2 * sacc;
    for(int m = 32; m >= 1; m >>= 1) val += __shfl_xor(val, m, 64);
    if(lane == 0){
        float yi = val + qrho[row] * psh[row];
        if(ynew) ynew[row] = yi;          // last iteration's y is never consumed
        red[wave] = yi * psh[row];
    }
    __syncthreads();
    if(tid == 0) pty_write[blockIdx.x] = red[0] + red[1] + red[2] + red[3];
}

// ---------------- CG step 0 (bf16, no prologue): stage p0 + matvec ----------------
__launch_bounds__(256)
__global__ void k_step_h0(const unsigned short* __restrict__ Dh,
                          const float* __restrict__ l1p, const float* __restrict__ l2p,
                          float* __restrict__ wf, const float* __restrict__ p0,
                          float* __restrict__ ynew, float* __restrict__ pty_write){
    __shared__ float psh[NN];
    __shared__ float red[8];
    int tid = threadIdx.x;
    for(int k = 0; k < 4; ++k)
        ((float4*)psh)[tid + k*256] = ((const float4*)p0)[tid + k*256];
    __syncthreads();
    bf16_matvec_tail(Dh, l1p[0], l2p[0], wf, psh, red, ynew, pty_write);
}

// ---------------- CG step j>=1: prologue + y = A p (bf16 D) + pTy partial ----------------
__launch_bounds__(256)
__global__ void k_step_h(const unsigned short* __restrict__ Dh,
                         const float* __restrict__ l1p, const float* __restrict__ l2p,
                         float* __restrict__ wf,
                         const float* __restrict__ rold, const float* __restrict__ pold,
                         const float* __restrict__ xold, const float* __restrict__ yold,
                         float* __restrict__ rnew, float* __restrict__ pnew,
                         float* __restrict__ xnew, float* __restrict__ ynew,
                         const float* __restrict__ pty_read, float* __restrict__ pty_write){
    __shared__ float psh[NN];
    __shared__ float red[8];
    cg_prologue(wf, rold, pold, xold, yold, rnew, pnew, xnew, pty_read, psh, red);
    bf16_matvec_tail(Dh, l1p[0], l2p[0], wf, psh, red, ynew, pty_write);
}

// ---------------- CG step fp32 fallback (do_pro selects prologue) ----------------
__launch_bounds__(256)
__global__ void k_step_f(const float* __restrict__ D,
                         const float* __restrict__ l1p, const float* __restrict__ l2p,
                         float* __restrict__ wf,
                         const float* __restrict__ rold, const float* __restrict__ pold,
                         const float* __restrict__ xold, const float* __restrict__ yold,
                         float* __restrict__ rnew, float* __restrict__ pnew,
                         float* __restrict__ xnew, float* __restrict__ ynew,
                         const float* __restrict__ pty_read, float* __restrict__ pty_write,
                         int do_pro){
    __shared__ float psh[NN];
    __shared__ float red[8];
    int tid = threadIdx.x;
    if(do_pro){
        cg_prologue(wf, rold, pold, xold, yold, rnew, pnew, xnew, pty_read, psh, red);
    } else {
        for(int k = 0; k < 4; ++k)
            ((float4*)psh)[tid + k*256] = ((const float4*)pold)[tid + k*256];
        __syncthreads();
    }
    float l1 = l1p[0], l2 = l2p[0];
    int wave = tid >> 6, lane = tid & 63;
    int row = blockIdx.x * 4 + wave;
    int h = row >> 6, u = row & 63;
    const float* qrho = wf + OFF_QRHO;
    const float* StS  = wf + OFF_STS;
    const float* Drow = D + (size_t)row * NN;
    float dacc = 0.f;
    for(int j = 0; j < 16; ++j){
        int c0 = j*256 + lane*4;
        float4 dv = *(const float4*)(Drow + c0);
        float4 pa = *(const float4*)(psh + c0);
        dacc += dv.x*pa.x + dv.y*pa.y + dv.z*pa.z + dv.w*pa.w;
    }
    float sacc = StS[u*64 + lane] * psh[h*64 + lane];
    float val = l1 * dacc + l2 * sacc;
    for(int m = 32; m >= 1; m >>= 1) val += __shfl_xor(val, m, 64);
    if(lane == 0){
        float yi = val + qrho[row] * psh[row];
        ynew[row] = yi;
        red[wave] = yi * psh[row];
    }
    __syncthreads();
    if(tid == 0) pty_write[blockIdx.x] = red[0] + red[1] + red[2] + red[3];
}

// ---------------- SVT: register-resident Brent-Luk Jacobi + final CG update fused ----------------
// 512 threads = 32 groups x 16 sublanes; each sublane owns 4 rows (one float4).
// R8 A/B: 256-thr variant loses (bank conflicts x3). Keep sl*4 / 8 waves.
#define P_MA(par) (POOL + (par)*2176)
#define P_MB(par) (POOL + 4352 + (par)*2176)
#define P_XSH     (POOL + 8704)
#define P_TSH     (POOL)
#define P_WC      (POOL + 4352)
#define DOT4(u,v) ((u).x*(v).x + (u).y*(v).y + (u).z*(v).z + (u).w*(v).w)

__launch_bounds__(512)
__global__ void k_svt(const float* __restrict__ thP, const float* __restrict__ vp,
                      const float* __restrict__ netap,
                      float* __restrict__ wf,
                      const float* __restrict__ rlast, const float* __restrict__ plast,
                      const float* __restrict__ xlast,
                      const float* __restrict__ ptyp,
                      float* __restrict__ out){
    __shared__ float POOL[12800];
    __shared__ float s2[64], coef3[64];
    __shared__ float smax_sh;
    __shared__ float redv[16];
    int tid = threadIdx.x;
    float* Xsh = P_XSH;

    // fused final CG update: alpha_last = rz_last / pTy_last ; X = x + alpha*p + thP
    {
        const float* dinv = wf + OFF_DINV;
        float part = 0.f;
        #pragma unroll
        for(int k = 0; k < 2; ++k){
            float4 r4 = ((const float4*)rlast)[tid + k*512];
            float4 d4 = ((const float4*)dinv)[tid + k*512];
            part += r4.x*r4.x*d4.x + r4.y*r4.y*d4.y + r4.z*r4.z*d4.z + r4.w*r4.w*d4.w;
        }
        float pp = ptyp[tid] + ptyp[tid + 512];
        for(int m = 32; m >= 1; m >>= 1){
            part += __shfl_xor(part, m, 64);
            pp   += __shfl_xor(pp, m, 64);
        }
        if((tid & 63) == 0){ redv[tid >> 6] = part; redv[8 + (tid >> 6)] = pp; }
        __syncthreads();
        float rz = redv[0] + redv[1] + redv[2] + redv[3]
                 + redv[4] + redv[5] + redv[6] + redv[7];
        float ptys = redv[8] + redv[9] + redv[10] + redv[11]
                   + redv[12] + redv[13] + redv[14] + redv[15];
        float a = rz / ptys;
        #pragma unroll
        for(int k = 0; k < 2; ++k){
            float4 x4 = ((const float4*)xlast)[tid + k*512];
            float4 p4 = ((const float4*)plast)[tid + k*512];
            float4 t4 = ((const float4*)thP)[tid + k*512];
            float4 v;
            v.x = x4.x + a*p4.x + t4.x;  v.y = x4.y + a*p4.y + t4.y;
            v.z = x4.z + a*p4.z + t4.z;  v.w = x4.w + a*p4.w + t4.w;
            ((float4*)Xsh)[tid + k*512] = v;
        }
    }
    __syncthreads();

    int g  = tid >> 4;      // group 0..31 (one aligned 16-lane DPP row)
    int sl = tid & 15;      // sub-lane: rows sl*4 .. sl*4+3
    float4 A, B;
    {
        int ca = 2*g, cb = 2*g + 1, r0 = sl*4;
        A.x = Xsh[(r0+0)*64+ca]; A.y = Xsh[(r0+1)*64+ca];
        A.z = Xsh[(r0+2)*64+ca]; A.w = Xsh[(r0+3)*64+ca];
        B.x = Xsh[(r0+0)*64+cb]; B.y = Xsh[(r0+1)*64+cb];
        B.z = Xsh[(r0+2)*64+cb]; B.w = Xsh[(r0+3)*64+cb];
    }
    float aa = rsum16(DOT4(A,A));
    float bb = rsum16(DOT4(B,B));

    const int total = NSWEEP * 63;
    for(int gr = 0; gr < total; ++gr){
        float cc = rsum16(DOT4(A,B));
        // branch-free angle, 3 transcendentals:
        // d=bb-aa; s=sqrt(d^2+4c^2); t = sgn(d)*2c/(|d|+s)
        float dd = bb - aa;
        float c2 = cc + cc;
        float s  = __builtin_amdgcn_sqrtf(__builtin_fmaf(dd, dd, c2*c2));
        float t0 = c2 * __builtin_amdgcn_rcpf(fabsf(dd) + s + 1e-30f);
        float t  = (dd < 0.f) ? -t0 : t0;
        float cs = __builtin_amdgcn_rsqf(__builtin_fmaf(t, t, 1.f));
        float sn = t * cs;
        float naN = aa - t*cc;      // rotated-A squared norm (Golub update)
        float nbN = bb + t*cc;      // rotated-B squared norm
        if(gr != total - 1){
            int par = gr & 1;
            float* MAp = P_MA(par);
            float* MBp = P_MB(par);
            // rotate & ship outgoing B first (overlap write latency with A rotation)
            float4 nb;
            nb.x = sn*A.x + cs*B.x; nb.y = sn*A.y + cs*B.y;
            nb.z = sn*A.z + cs*B.z; nb.w = sn*A.w + cs*B.w;
            float* cbB = (g == 0) ? (MAp + 1*MCS) : (MBp + (g-1)*MCS);
            *(float4*)(cbB + sl*4) = nb;
            if(sl == 0) cbB[64] = nbN;
            float4 na;
            na.x = cs*A.x - sn*B.x; na.y = cs*A.y - sn*B.y;
            na.z = cs*A.z - sn*B.z; na.w = cs*A.w - sn*B.w;
            if(g >= 1 && g <= 30){
                float* cbA = MAp + (g+1)*MCS;
                *(float4*)(cbA + sl*4) = na;
                if(sl == 0) cbA[64] = naN;
            }
            __syncthreads();
            float4 nA = na;  float nAa = naN;   // g==0 keeps rotated A
            float4 nB = na;  float nBb = naN;   // g==31: new B = rotated A
            if(g >= 1){
                const float* ra = MAp + g*MCS;
                nA = *(const float4*)(ra + sl*4);
                nAa = ra[64];
            }
            if(g <= 30){
                const float* rb = MBp + g*MCS;
                nB = *(const float4*)(rb + sl*4);
                nBb = rb[64];
            }
            A = nA; B = nB; aa = nAa; bb = nBb;
        } else {
            float4 na;
            na.x = cs*A.x - sn*B.x; na.y = cs*A.y - sn*B.y;
            na.z = cs*A.z - sn*B.z; na.w = cs*A.w - sn*B.w;
            float4 nbf;
            nbf.x = sn*A.x + cs*B.x; nbf.y = sn*A.y + cs*B.y;
            nbf.z = sn*A.z + cs*B.z; nbf.w = sn*A.w + cs*B.w;
            A = na; B = nbf;
        }
    }
    // final column norms (exact, drift-free) + store W to LDS
    {
        float fa = rsum16(DOT4(A,A));
        float fb = rsum16(DOT4(B,B));
        __syncthreads();   // mailbox reads done before Wc (aliases MB) written
        float* Wc = P_WC;
        *(float4*)(Wc + (2*g)*MCS + sl*4)   = A;
        *(float4*)(Wc + (2*g+1)*MCS + sl*4) = B;
        if(sl == 0){ s2[2*g] = fa; s2[2*g+1] = fb; }
    }
    __syncthreads();
    if(tid < 64){
        float v = s2[tid];
        for(int m = 32; m >= 1; m >>= 1) v = fmaxf(v, __shfl_xor(v, m, 64));
        if(tid == 0) smax_sh = sqrtf(v);
    }
    __syncthreads();
    if(tid < 64){
        float s = sqrtf(s2[tid]);
        float v = vp[0];
        float tau = 0.4f / (1.f + expf(-v));     // sigmoid(v)*COEF_GAMMA
        float thr = tau * smax_sh;
        coef3[tid] = (s > thr && s > 1e-20f) ? (s - thr) / (s*s*s) : 0.f;
    }
    __syncthreads();

    const float* Wc = P_WC;
    float* Tsh = P_TSH;
    // R1: T'[k][j] = coef3[k] * sum_r Wc[k][r] * Xsh[r][j]   (8 cols per thread)
    {
        int kk = tid >> 3;
        int j0 = (tid & 7) * 8;
        float acc[8];
        #pragma unroll
        for(int j = 0; j < 8; ++j) acc[j] = 0.f;
        for(int r = 0; r < 64; ++r){
            float wk = Wc[kk*MCS + r];
            const float* xr = Xsh + r*64 + j0;
            float4 x0 = *(const float4*)(xr);
            float4 x1 = *(const float4*)(xr + 4);
            acc[0]+=wk*x0.x; acc[1]+=wk*x0.y; acc[2]+=wk*x0.z; acc[3]+=wk*x0.w;
            acc[4]+=wk*x1.x; acc[5]+=wk*x1.y; acc[6]+=wk*x1.z; acc[7]+=wk*x1.w;
        }
        float c3 = coef3[kk];
        float* tr = Tsh + kk*64 + j0;
        float4 t0, t1;
        t0.x = c3*acc[0]; t0.y = c3*acc[1]; t0.z = c3*acc[2]; t0.w = c3*acc[3];
        t1.x = c3*acc[4]; t1.y = c3*acc[5]; t1.z = c3*acc[6]; t1.w = c3*acc[7];
        *(float4*)(tr)     = t0;
        *(float4*)(tr + 4) = t1;
    }
    __syncthreads();

    // R2: Ltmp[i][j] = sum_k Wc[k][i] * T'[k][j]; outputs   (8 cols per thread)
    {
        float neta = netap[0];
        int i  = tid >> 3;
        int j0 = (tid & 7) * 8;
        float acc[8];
        #pragma unroll
        for(int j = 0; j < 8; ++j) acc[j] = 0.f;
        for(int kk = 0; kk < 64; ++kk){
            float wik = Wc[kk*MCS + i];
            const float* tr = Tsh + kk*64 + j0;
            float4 t0 = *(const float4*)(tr);
            float4 t1 = *(const float4*)(tr + 4);
            acc[0]+=wik*t0.x; acc[1]+=wik*t0.y; acc[2]+=wik*t0.z; acc[3]+=wik*t0.w;
            acc[4]+=wik*t1.x; acc[5]+=wik*t1.y; acc[6]+=wik*t1.z; acc[7]+=wik*t1.w;
        }
        int n0 = i*64 + j0;
        #pragma unroll
        for(int c = 0; c < 2; ++c){
            float4 th = *(const float4*)(thP + n0 + 4*c);
            float4 lt, pt;
            lt.x = acc[4*c+0]; lt.y = acc[4*c+1]; lt.z = acc[4*c+2]; lt.w = acc[4*c+3];
            float4 xs = *(const float4*)(Xsh + n0 + 4*c);
            pt.x = th.x + neta * (xs.x - th.x - lt.x);
            pt.y = th.y + neta * (xs.y - th.y - lt.y);
            pt.z = th.z + neta * (xs.z - th.z - lt.z);
            pt.w = th.w + neta * (xs.w - th.w - lt.w);
            *(float4*)(out + n0 + 4*c)      = lt;
            *(float4*)(out + NN + n0 + 4*c) = pt;
        }
    }
}

extern "C" void kernel_launch(void* const* d_in, const int* in_sizes, int n_in,
                              void* d_out, int out_size, void* d_ws, size_t ws_size,
                              hipStream_t stream){
    const float* inp  = (const float*)d_in[0];
    const float* L    = (const float*)d_in[1];
    const int*   mask = (const int*)  d_in[2];
    const float* D    = (const float*)d_in[3];
    const float* thP  = (const float*)d_in[4];
    const float* vS   = (const float*)d_in[5];
    const float* neta = (const float*)d_in[6];
    const float* l1   = (const float*)d_in[7];
    const float* l2   = (const float*)d_in[8];
    const float* rho  = (const float*)d_in[9];
    const float* S    = (const float*)d_in[10];
    float* wf = (float*)d_ws;
    float* out = (float*)d_out;
    const bool use_bf16 = (ws_size >= WS_NEED_BF16);
    unsigned short* Dh = (unsigned short*)((char*)d_ws + DH_OFF_BYTES);

    float* Xb[2]  = { wf + OFF_X0, wf + OFF_X1 };
    float* Rb[2]  = { wf + OFF_R0, wf + OFF_R1 };
    float* Pb[2]  = { wf + OFF_P0, wf + OFF_P1 };
    float* Yb[2]  = { wf + OFF_Y0, wf + OFF_Y1 };
    float* pty[2] = { wf + OFF_PTY0, wf + OFF_PTY1 };

    if(use_bf16){
        // streaming convert + prep, then all-bf16 CG (iteration 0 included)
        k_conv<<<2064, 256, 0, stream>>>(D, Dh, inp, L, mask, thP, S, l2, rho, wf);
        k_step_h0<<<1024, 256, 0, stream>>>(Dh, l1, l2, wf, Pb[0], Yb[0], pty[0]);
        for(int j = 1; j < NITER; ++j){
            int ro = (j+1)&1, wr = j&1;
            k_step_h<<<1024, 256, 0, stream>>>(Dh, l1, l2, wf,
                Rb[ro], Pb[ro], Xb[ro], Yb[ro],
                Rb[wr], Pb[wr], Xb[wr],
                (j < NITER-1) ? Yb[wr] : (float*)nullptr,   // last y unused
                pty[(j-1)&1], pty[j&1]);
        }
    } else {
        k_prep<<<16, 256, 0, stream>>>(inp, L, mask, thP, S, l2, rho, wf);
        k_step_f<<<1024, 256, 0, stream>>>(D, l1, l2, wf,
            Rb[0], Pb[0], Xb[0], Yb[0], Rb[1], Pb[1], Xb[1], Yb[0],
            pty[0], pty[0], 0);
        for(int j = 1; j < NITER; ++j){
            int ro = (j+1)&1, wr = j&1;
            k_step_f<<<1024, 256, 0, stream>>>(D, l1, l2, wf,
                Rb[ro], Pb[ro], Xb[ro], Yb[ro],
                Rb[wr], Pb[wr], Xb[wr], Yb[wr],
                pty[(j-1)&1], pty[j&1], 1);
        }
    }
    // last write parity = (NITER-1)&1  (NITER=3 -> 0)
    const int lp = (NITER-1)&1;
    k_svt<<<1, 512, 0, stream>>>(thP, vS, neta, wf, Rb[lp], Pb[lp], Xb[lp],
                                 pty[lp], out);
}